// Round 7
// baseline (1176.295 us; speedup 1.0000x reference)
//
#include <hip/hip_runtime.h>
#include <math.h>

// ---------------------------------------------------------------------------
// GTAN2 R7: issue-early global loads (single-buffered prefetch: loads for
// kc+1 issued right after barrier-B of kc) in k_mm_bf + k_mmfc; hop-0 H-path
// eliminated (h==x at hop 0 => hlin==xnew, h1a==xa2a); fc2 2-term (h_hi only).
// Hop H path stays 3-term. k_agg and epilogues unchanged from R6.
// ---------------------------------------------------------------------------

typedef __attribute__((ext_vector_type(8))) short short8;
typedef __attribute__((ext_vector_type(4))) float f32x4;
#define MFMA16 __builtin_amdgcn_mfma_f32_16x16x32_bf16

__device__ __forceinline__ float lrelu02(float v) { return v > 0.f ? v : 0.2f * v; }

__device__ __forceinline__ float2 bf2f2(unsigned int v) {
    return make_float2(__uint_as_float(v << 16), __uint_as_float(v & 0xffff0000u));
}
__device__ __forceinline__ unsigned int f2bf(float f) {  // RNE bf16
    unsigned int u = __float_as_uint(f);
    u += 0x7fffu + ((u >> 16) & 1u);
    return u >> 16;
}
__device__ __forceinline__ float hi_part(float f) {  // truncate mantissa to bf16
    return __uint_as_float(__float_as_uint(f) & 0xffff0000u);
}
__device__ __forceinline__ uint4 pack_hi(const float4& a, const float4& b) {
    uint4 r;
    r.x = (__float_as_uint(a.x) >> 16) | (__float_as_uint(a.y) & 0xffff0000u);
    r.y = (__float_as_uint(a.z) >> 16) | (__float_as_uint(a.w) & 0xffff0000u);
    r.z = (__float_as_uint(b.x) >> 16) | (__float_as_uint(b.y) & 0xffff0000u);
    r.w = (__float_as_uint(b.z) >> 16) | (__float_as_uint(b.w) & 0xffff0000u);
    return r;
}
__device__ __forceinline__ uint4 pack_lo(const float4& a, const float4& b) {
    uint4 r;
    r.x = f2bf(a.x - hi_part(a.x)) | (f2bf(a.y - hi_part(a.y)) << 16);
    r.y = f2bf(a.z - hi_part(a.z)) | (f2bf(a.w - hi_part(a.w)) << 16);
    r.z = f2bf(b.x - hi_part(b.x)) | (f2bf(b.y - hi_part(b.y)) << 16);
    r.w = f2bf(b.z - hi_part(b.z)) | (f2bf(b.w - hi_part(b.w)) << 16);
    return r;
}

// ---------------- CSR build ----------------
__global__ __launch_bounds__(256) void k_count(const int* __restrict__ s, int* __restrict__ cnt, int E) {
    int e = blockIdx.x * 256 + threadIdx.x;
    if (e < E) atomicAdd(&cnt[s[e]], 1);
}

__global__ __launch_bounds__(256) void k_scan1(const int* __restrict__ cnt, int* __restrict__ bs, int N) {
    __shared__ int sh[256];
    int idx = blockIdx.x * 256 + threadIdx.x;
    sh[threadIdx.x] = (idx < N) ? cnt[idx] : 0;
    __syncthreads();
#pragma unroll
    for (int off = 128; off; off >>= 1) {
        if (threadIdx.x < off) sh[threadIdx.x] += sh[threadIdx.x + off];
        __syncthreads();
    }
    if (threadIdx.x == 0) bs[blockIdx.x] = sh[0];
}

__global__ __launch_bounds__(256) void k_scan2(int* __restrict__ bs, int G) {
    __shared__ int sh[256];
    int t = threadIdx.x;
    int v = (t < G) ? bs[t] : 0;
    sh[t] = v;
    __syncthreads();
    int val = v;
#pragma unroll
    for (int off = 1; off < 256; off <<= 1) {
        int o = (t >= off) ? sh[t - off] : 0;
        __syncthreads();
        val += o; sh[t] = val;
        __syncthreads();
    }
    if (t < G) bs[t] = val - v;  // exclusive
}

__global__ __launch_bounds__(256) void k_scan3(const int* __restrict__ cnt, const int* __restrict__ bs,
                                               int* __restrict__ rp, int N) {
    __shared__ int sh[256];
    int t = threadIdx.x;
    int idx = blockIdx.x * 256 + t;
    int v = (idx < N) ? cnt[idx] : 0;
    sh[t] = v;
    __syncthreads();
    int val = v;
#pragma unroll
    for (int off = 1; off < 256; off <<= 1) {
        int o = (t >= off) ? sh[t - off] : 0;
        __syncthreads();
        val += o; sh[t] = val;
        __syncthreads();
    }
    if (idx <= N) rp[idx] = val - v + bs[blockIdx.x];
}

__global__ __launch_bounds__(256) void k_scatter(const int* __restrict__ s, const int* __restrict__ t,
                                                 const int* __restrict__ rp, int* __restrict__ cursor,
                                                 int* __restrict__ t_sorted, int E) {
    int e = blockIdx.x * 256 + threadIdx.x;
    if (e < E) {
        int u = s[e];
        int pos = atomicAdd(&cursor[u], 1);
        t_sorted[rp[u] + pos] = t[e];
    }
}

// ---------------- W split for hop weights ----------------
__global__ __launch_bounds__(256) void k_wsplit(const float* __restrict__ W,
                                                unsigned short* __restrict__ Whi,
                                                unsigned short* __restrict__ Wlo, int total) {
    int i = blockIdx.x * 256 + threadIdx.x;
    if (i < total) {
        float f = W[i];
        unsigned int u = __float_as_uint(f);
        Whi[i] = (unsigned short)(u >> 16);
        Wlo[i] = (unsigned short)f2bf(f - __uint_as_float(u & 0xffff0000u));
    }
}

// ---------------- fc1/fc2 MFMA GEMM ----------------
// MODE 1 = fc1: fp32 X [N,256] & fp32 W [128,256], 3-term, relu, split out.
// MODE 2 = fc2: bf16 X [N,128] (h_hi) & fp32 W [64,128], 2-term, fp32 out.
template <int MODE>
__global__ __launch_bounds__(256) void k_mmfc(
    const float* __restrict__ Xf,
    const unsigned short* __restrict__ Xhi,
    const float* __restrict__ Wf, const float* __restrict__ bias,
    float* __restrict__ Yf, unsigned short* __restrict__ Yhi, unsigned short* __restrict__ Ylo,
    int N) {
    constexpr int K = (MODE == 1) ? 256 : 128;
    constexpr int NCOLS = (MODE == 1) ? 128 : 64;
    constexpr int KC = K / 32;
    __shared__ unsigned short lds[2 * 128 * 64];  // 32 KB
    unsigned short* Xs = lds;
    unsigned short* Wt = lds + 128 * 64;

    const int tid = threadIdx.x;
    const int r0 = blockIdx.x * 128;
    const int srow = tid & 127;
    const int sp = tid >> 7;  // MODE1: khalf; MODE2: 0 = X-stager, both = W-khalf
    const int xrow = r0 + srow;
    const bool xok = xrow < N;
    const bool wok = srow < NCOLS;

    const int lane = tid & 63;
    const int w = tid >> 6;
    const int wr = (w >> 1) * 64, wc = (w & 1) * 64;
    const int frow = lane & 15;
    const int fk = lane >> 4;
    const int q4 = lane >> 4;

    f32x4 acc[4][4];
#pragma unroll
    for (int i = 0; i < 4; ++i)
#pragma unroll
        for (int j = 0; j < 4; ++j) acc[i][j] = (f32x4){0.f, 0.f, 0.f, 0.f};

    const float4 z4 = make_float4(0.f, 0.f, 0.f, 0.f);
    const uint4 zz = make_uint4(0, 0, 0, 0);

    // preload kc = 0
    float4 xv[4], wv[4];
    uint4 xg[4];
    if constexpr (MODE == 1) {
        const float* xp = Xf + (size_t)xrow * K + sp * 16;
        const float* wp = Wf + (size_t)srow * K + sp * 16;
#pragma unroll
        for (int q = 0; q < 4; ++q) {
            xv[q] = xok ? *(const float4*)(xp + q * 4) : z4;
            wv[q] = wok ? *(const float4*)(wp + q * 4) : z4;
        }
    } else {
        const unsigned short* xp = Xhi + (size_t)xrow * K;
        const float* wp = Wf + (size_t)srow * K + sp * 16;
#pragma unroll
        for (int g = 0; g < 4; ++g) xg[g] = (xok && sp == 0) ? ((const uint4*)xp)[g] : zz;
#pragma unroll
        for (int q = 0; q < 4; ++q) wv[q] = wok ? *(const float4*)(wp + q * 4) : z4;
    }

#pragma unroll
    for (int kc = 0; kc < KC; ++kc) {
        __syncthreads();
        if constexpr (MODE == 1) {
#pragma unroll
            for (int j = 0; j < 2; ++j) {
                int g = sp * 2 + j;
                *(uint4*)(Xs + srow * 64 + ((g) ^ (srow & 7)) * 8)     = pack_hi(xv[2 * j], xv[2 * j + 1]);
                *(uint4*)(Xs + srow * 64 + ((4 | g) ^ (srow & 7)) * 8) = pack_lo(xv[2 * j], xv[2 * j + 1]);
                *(uint4*)(Wt + srow * 64 + ((g) ^ (srow & 7)) * 8)     = pack_hi(wv[2 * j], wv[2 * j + 1]);
                *(uint4*)(Wt + srow * 64 + ((4 | g) ^ (srow & 7)) * 8) = pack_lo(wv[2 * j], wv[2 * j + 1]);
            }
        } else {
            if (sp == 0) {
#pragma unroll
                for (int g = 0; g < 4; ++g) {
                    int p = g ^ (srow & 7);
                    *(uint4*)(Xs + srow * 64 + p * 8) = xg[g];
                }
            }
#pragma unroll
            for (int j = 0; j < 2; ++j) {
                int g = sp * 2 + j;
                *(uint4*)(Wt + srow * 64 + ((g) ^ (srow & 7)) * 8)     = pack_hi(wv[2 * j], wv[2 * j + 1]);
                *(uint4*)(Wt + srow * 64 + ((4 | g) ^ (srow & 7)) * 8) = pack_lo(wv[2 * j], wv[2 * j + 1]);
            }
        }
        __syncthreads();

        // issue-early loads for kc+1 (registers are free after LDS write)
        if (kc < KC - 1) {
            if constexpr (MODE == 1) {
                const float* xp = Xf + (size_t)xrow * K + (kc + 1) * 32 + sp * 16;
                const float* wp = Wf + (size_t)srow * K + (kc + 1) * 32 + sp * 16;
#pragma unroll
                for (int q = 0; q < 4; ++q) {
                    xv[q] = xok ? *(const float4*)(xp + q * 4) : z4;
                    wv[q] = wok ? *(const float4*)(wp + q * 4) : z4;
                }
            } else {
                const unsigned short* xp = Xhi + (size_t)xrow * K + (kc + 1) * 32;
                const float* wp = Wf + (size_t)srow * K + (kc + 1) * 32 + sp * 16;
#pragma unroll
                for (int g = 0; g < 4; ++g) xg[g] = (xok && sp == 0) ? ((const uint4*)xp)[g] : zz;
#pragma unroll
                for (int q = 0; q < 4; ++q) wv[q] = wok ? *(const float4*)(wp + q * 4) : z4;
            }
        }

        short8 ah[4], bh[4], bl[4];
#pragma unroll
        for (int ri = 0; ri < 4; ++ri) {
            int row = wr + ri * 16 + frow;
            ah[ri] = *(const short8*)(Xs + row * 64 + ((fk) ^ (row & 7)) * 8);
        }
#pragma unroll
        for (int ci = 0; ci < 4; ++ci) {
            int col = wc + ci * 16 + frow;
            bh[ci] = *(const short8*)(Wt + col * 64 + ((fk) ^ (col & 7)) * 8);
            bl[ci] = *(const short8*)(Wt + col * 64 + ((4 | fk) ^ (col & 7)) * 8);
        }
        if constexpr (MODE == 1) {
            short8 al[4];
#pragma unroll
            for (int ri = 0; ri < 4; ++ri) {
                int row = wr + ri * 16 + frow;
                al[ri] = *(const short8*)(Xs + row * 64 + ((4 | fk) ^ (row & 7)) * 8);
            }
#pragma unroll
            for (int ri = 0; ri < 4; ++ri)
#pragma unroll
                for (int ci = 0; ci < 4; ++ci) {
                    acc[ri][ci] = MFMA16(ah[ri], bh[ci], acc[ri][ci], 0, 0, 0);
                    acc[ri][ci] = MFMA16(ah[ri], bl[ci], acc[ri][ci], 0, 0, 0);
                    acc[ri][ci] = MFMA16(al[ri], bh[ci], acc[ri][ci], 0, 0, 0);
                }
        } else {
#pragma unroll
            for (int ri = 0; ri < 4; ++ri)
#pragma unroll
                for (int ci = 0; ci < 4; ++ci) {
                    acc[ri][ci] = MFMA16(ah[ri], bh[ci], acc[ri][ci], 0, 0, 0);
                    acc[ri][ci] = MFMA16(ah[ri], bl[ci], acc[ri][ci], 0, 0, 0);
                }
        }
    }

#pragma unroll
    for (int ci = 0; ci < 4; ++ci) {
        int col = wc + ci * 16 + frow;
        float bcol = (col < NCOLS) ? bias[col] : 0.f;
#pragma unroll
        for (int ri = 0; ri < 4; ++ri) {
            f32x4 v = acc[ri][ci];
#pragma unroll
            for (int reg = 0; reg < 4; ++reg) {
                int grow = r0 + wr + ri * 16 + q4 * 4 + reg;
                float val = v[reg] + bcol;
                if (grow < N && col < NCOLS) {
                    if constexpr (MODE == 1) {
                        val = fmaxf(val, 0.f);
                        Yhi[(size_t)grow * 128 + col] = (unsigned short)(__float_as_uint(val) >> 16);
                        Ylo[(size_t)grow * 128 + col] = (unsigned short)f2bf(val - hi_part(val));
                    } else {
                        Yf[(size_t)grow * 64 + col] = val;
                    }
                }
            }
        }
    }
}

// ---------------- hop GEMM: dual-source; X path 3-term, H path 2-term -------
__global__ __launch_bounds__(256) void k_mm_bf(
    const unsigned short* __restrict__ Xhi0, const unsigned short* __restrict__ Xlo0, int nblk0,
    const unsigned short* __restrict__ Hhi1,
    const unsigned short* __restrict__ Whi, const unsigned short* __restrict__ Wlo,
    const float* __restrict__ bias,
    unsigned short* __restrict__ Yb0, unsigned short* __restrict__ Yb1, int N,
    const float* __restrict__ dA0, float* __restrict__ oA0,
    const float* __restrict__ dB0, float* __restrict__ oB0,
    const float* __restrict__ dA1, float* __restrict__ oA1) {
    __shared__ unsigned short lds[128 * 128 + 1024];  // 34 KB
    unsigned short* Xs = lds;
    unsigned short* Wt = lds + 128 * 64;

    const int tid = threadIdx.x;
    const bool second = (int)blockIdx.x >= nblk0;
    const int bx = second ? (int)blockIdx.x - nblk0 : (int)blockIdx.x;
    const int r0 = bx * 128;
    const int srow = tid & 127;
    const int splane = tid >> 7;
    const unsigned short* Xp = second ? (splane ? (const unsigned short*)nullptr : Hhi1)
                                      : (splane ? Xlo0 : Xhi0);
    const unsigned short* Wp = splane ? Wlo : Whi;
    unsigned short* Yb = second ? Yb1 : Yb0;
    const int xrow = r0 + srow;
    const bool xok = (Xp != nullptr) && (xrow < N);

    const int lane = tid & 63;
    const int w = tid >> 6;
    const int wr = (w >> 1) * 64, wc = (w & 1) * 64;
    const int frow = lane & 15;
    const int fk = lane >> 4;
    const int q4 = lane >> 4;

    f32x4 acc[4][4];
#pragma unroll
    for (int i = 0; i < 4; ++i)
#pragma unroll
        for (int j = 0; j < 4; ++j) acc[i][j] = (f32x4){0.f, 0.f, 0.f, 0.f};

    const uint4 zz = make_uint4(0, 0, 0, 0);
    uint4 xg[4], wg[4];
    {
        const uint4* xsrc = (const uint4*)(Xp + (size_t)xrow * 128);
        const uint4* wsrc = (const uint4*)(Wp + (size_t)srow * 128);
#pragma unroll
        for (int g = 0; g < 4; ++g) {
            xg[g] = xok ? xsrc[g] : zz;
            wg[g] = wsrc[g];
        }
    }

#pragma unroll
    for (int kc = 0; kc < 4; ++kc) {
        __syncthreads();
        if (!second || splane == 0) {
#pragma unroll
            for (int g = 0; g < 4; ++g) {
                int p = ((splane << 2) | g) ^ (srow & 7);
                *(uint4*)(Xs + srow * 64 + p * 8) = xg[g];
            }
        }
#pragma unroll
        for (int g = 0; g < 4; ++g) {
            int p = ((splane << 2) | g) ^ (srow & 7);
            *(uint4*)(Wt + srow * 64 + p * 8) = wg[g];
        }
        __syncthreads();

        // issue-early loads for kc+1
        if (kc < 3) {
            const uint4* xsrc = (const uint4*)(Xp + (size_t)xrow * 128 + (kc + 1) * 32);
            const uint4* wsrc = (const uint4*)(Wp + (size_t)srow * 128 + (kc + 1) * 32);
#pragma unroll
            for (int g = 0; g < 4; ++g) {
                xg[g] = xok ? xsrc[g] : zz;
                wg[g] = wsrc[g];
            }
        }

        short8 ah[4], bh[4], bl[4];
#pragma unroll
        for (int ri = 0; ri < 4; ++ri) {
            int row = wr + ri * 16 + frow;
            ah[ri] = *(const short8*)(Xs + row * 64 + (fk ^ (row & 7)) * 8);
        }
#pragma unroll
        for (int ci = 0; ci < 4; ++ci) {
            int col = wc + ci * 16 + frow;
            bh[ci] = *(const short8*)(Wt + col * 64 + (fk ^ (col & 7)) * 8);
            bl[ci] = *(const short8*)(Wt + col * 64 + ((4 | fk) ^ (col & 7)) * 8);
        }
        if (!second) {
            short8 al[4];
#pragma unroll
            for (int ri = 0; ri < 4; ++ri) {
                int row = wr + ri * 16 + frow;
                al[ri] = *(const short8*)(Xs + row * 64 + ((4 | fk) ^ (row & 7)) * 8);
            }
#pragma unroll
            for (int ri = 0; ri < 4; ++ri)
#pragma unroll
                for (int ci = 0; ci < 4; ++ci) {
                    acc[ri][ci] = MFMA16(ah[ri], bh[ci], acc[ri][ci], 0, 0, 0);
                    acc[ri][ci] = MFMA16(ah[ri], bl[ci], acc[ri][ci], 0, 0, 0);
                    acc[ri][ci] = MFMA16(al[ri], bh[ci], acc[ri][ci], 0, 0, 0);
                }
        } else {
#pragma unroll
            for (int ri = 0; ri < 4; ++ri)
#pragma unroll
                for (int ci = 0; ci < 4; ++ci) {
                    acc[ri][ci] = MFMA16(ah[ri], bh[ci], acc[ri][ci], 0, 0, 0);
                    acc[ri][ci] = MFMA16(ah[ri], bl[ci], acc[ri][ci], 0, 0, 0);
                }
        }
    }

    // ---- epilogue: bias + dots + bf16 LDS staging (dword-XOR swizzle) ----
    const float* dA = second ? dA1 : dA0;
    const float* dB = second ? nullptr : dB0;
    unsigned short* So = lds;                       // [128][128] bf16, swizzled
    float* dotbuf = (float*)(lds + 128 * 128);      // 2 KB: [2][128][2]

    float dotA[4][4] = {}, dotB[4][4] = {};
    __syncthreads();  // all waves done reading Xs/Wt
#pragma unroll
    for (int ci = 0; ci < 4; ++ci) {
        int col = wc + ci * 16 + frow;
        float bcol = bias[col];
        float dAc = dA ? dA[col] : 0.f;
        float dBc = dB ? dB[col] : 0.f;
#pragma unroll
        for (int ri = 0; ri < 4; ++ri) {
            f32x4 v = acc[ri][ci];
#pragma unroll
            for (int reg = 0; reg < 4; ++reg) {
                float val = v[reg] + bcol;
                int row = wr + ri * 16 + q4 * 4 + reg;
                int dw = (col >> 1) ^ ((row & 12) << 1);
                So[row * 128 + dw * 2 + (col & 1)] = (unsigned short)f2bf(val);
                dotA[ri][reg] = fmaf(val, dAc, dotA[ri][reg]);
                dotB[ri][reg] = fmaf(val, dBc, dotB[ri][reg]);
            }
        }
    }
#pragma unroll
    for (int m = 1; m < 16; m <<= 1)
#pragma unroll
        for (int ri = 0; ri < 4; ++ri)
#pragma unroll
            for (int reg = 0; reg < 4; ++reg) {
                dotA[ri][reg] += __shfl_xor(dotA[ri][reg], m, 64);
                dotB[ri][reg] += __shfl_xor(dotB[ri][reg], m, 64);
            }
    if (frow == 0) {
#pragma unroll
        for (int ri = 0; ri < 4; ++ri)
#pragma unroll
            for (int reg = 0; reg < 4; ++reg) {
                int rl = wr + ri * 16 + q4 * 4 + reg;
                dotbuf[(0 * 128 + rl) * 2 + (w & 1)] = dotA[ri][reg];
                dotbuf[(1 * 128 + rl) * 2 + (w & 1)] = dotB[ri][reg];
            }
    }
    __syncthreads();

    // cooperative full-line stores: 8 x uint4 per thread, rows dense
#pragma unroll
    for (int q = 0; q < 8; ++q) {
        int idx = q * 256 + tid;        // 0..2047
        int row = idx >> 4;
        int gc = idx & 15;
        int dwb = (gc * 4) ^ ((row & 12) << 1);
        uint4 vv = *(const uint4*)(So + row * 128 + dwb * 2);
        int grow = r0 + row;
        if (grow < N) *(uint4*)(Yb + (size_t)grow * 128 + gc * 8) = vv;
    }
    {
        int d = tid >> 7, rl = tid & 127;
        int grow = r0 + rl;
        float* oA = second ? oA1 : oA0;
        float* oB = second ? nullptr : oB0;
        if (grow < N) {
            float v = dotbuf[(d * 128 + rl) * 2] + dotbuf[(d * 128 + rl) * 2 + 1];
            if (d == 0) { if (oA) oA[grow] = v; }
            else        { if (oB) oB[grow] = v; }
        }
    }
}

// ---------------- aggregation: LDS-staged (t,w), 8-deep gather groups --------
__global__ __launch_bounds__(256) void k_agg(
    const unsigned short* __restrict__ xnb, const unsigned short* __restrict__ hbf,
    const float* __restrict__ x1a, const float* __restrict__ xa2a,
    const float* __restrict__ h1a, const int* __restrict__ rp,
    const int* __restrict__ ts,
    unsigned short* __restrict__ hhi, unsigned short* __restrict__ hlo, int N) {
    __shared__ uint2 ew[4][64];
    const int wid = threadIdx.x >> 6;
    const int lane = threadIdx.x & 63;
    const int u = blockIdx.x * 4 + wid;
    if (u >= N) return;  // no barriers below; per-wave LDS slice only
    const int l2 = lane << 1;
    float x1u = x1a[u];
    float w2 = expf(lrelu02(x1u + xa2a[u]));
    float2 xr = bf2f2(*(const unsigned int*)(xnb + (size_t)u * 128 + l2));
    float accx = w2 * xr.x, accy = w2 * xr.y;
    float div = w2;
    int p0 = rp[u], p1 = rp[u + 1];
    for (int base = p0; base < p1; base += 64) {
        int e = base + lane;
        uint2 pk = make_uint2(0u, 0u);  // t=0, w=0 pad: zero contribution
        if (e < p1) {
            int tv = ts[e];
            pk.x = (unsigned int)tv;
            pk.y = __float_as_uint(expf(lrelu02(x1u + h1a[tv])));
        }
        ew[wid][lane] = pk;
        int m = p1 - base; if (m > 64) m = 64;
        int m8 = (m + 7) & ~7;
        for (int j = 0; j < m8; j += 8) {
            uint2 q[8];
#pragma unroll
            for (int k = 0; k < 8; ++k) q[k] = ew[wid][j + k];
            unsigned int hv[8];
#pragma unroll
            for (int k = 0; k < 8; ++k)
                hv[k] = *(const unsigned int*)(hbf + (size_t)q[k].x * 128 + l2);
#pragma unroll
            for (int k = 0; k < 8; ++k) {
                float ww = __uint_as_float(q[k].y);
                float2 f = bf2f2(hv[k]);
                accx = fmaf(ww, f.x, accx);
                accy = fmaf(ww, f.y, accy);
                div += ww;
            }
        }
    }
    float ox = accx / div, oy = accy / div;
    ox = ox > 0.f ? ox : expf(ox) - 1.f;
    oy = oy > 0.f ? oy : expf(oy) - 1.f;
    unsigned int hx = __float_as_uint(ox), hy = __float_as_uint(oy);
    *(unsigned int*)(hhi + (size_t)u * 128 + l2) = (hx >> 16) | (hy & 0xffff0000u);
    float lox = ox - __uint_as_float(hx & 0xffff0000u);
    float loy = oy - __uint_as_float(hy & 0xffff0000u);
    *(unsigned int*)(hlo + (size_t)u * 128 + l2) = f2bf(lox) | (f2bf(loy) << 16);
}

// ---------------- launch ----------------
extern "C" void kernel_launch(void* const* d_in, const int* in_sizes, int n_in,
                              void* d_out, int out_size, void* d_ws, size_t ws_size,
                              hipStream_t stream) {
    const float* x_in = (const float*)d_in[0];
    const int*   s    = (const int*)d_in[1];
    const int*   t    = (const int*)d_in[2];
    const float* fc1W = (const float*)d_in[3];
    const float* fc1b = (const float*)d_in[4];
    const float* fcsW = (const float*)d_in[5];
    const float* fcsb = (const float*)d_in[6];
    const float* a1   = (const float*)d_in[7];
    const float* a2   = (const float*)d_in[8];
    const float* fc2W = (const float*)d_in[9];
    const float* fc2b = (const float*)d_in[10];

    const int N = in_sizes[0] / 256;  // 50000
    const int E = in_sizes[1];        // 800000
    const int G = (N + 255) / 256;
    const int NB = (N + 127) / 128;   // 391

    char* ws = (char*)d_ws;
    size_t off = 0;
    auto alloc = [&](size_t bytes) -> void* {
        void* p = ws + off;
        off += (bytes + 255) & ~(size_t)255;
        return p;
    };
    unsigned short* xbuf_hi = (unsigned short*)alloc((size_t)N * 128 * 2);
    unsigned short* xbuf_lo = (unsigned short*)alloc((size_t)N * 128 * 2);
    unsigned short* h_hi    = (unsigned short*)alloc((size_t)N * 128 * 2);
    unsigned short* h_lo    = (unsigned short*)alloc((size_t)N * 128 * 2);
    unsigned short* xnb     = (unsigned short*)alloc((size_t)N * 128 * 2);  // xnew bf16
    unsigned short* hbf     = (unsigned short*)alloc((size_t)N * 128 * 2);
    unsigned short* Whi = (unsigned short*)alloc((size_t)10 * 128 * 128 * 2);
    unsigned short* Wlo = (unsigned short*)alloc((size_t)10 * 128 * 128 * 2);
    float* x1a  = (float*)alloc((size_t)N * 4);
    float* xa2a = (float*)alloc((size_t)N * 4);
    float* h1a  = (float*)alloc((size_t)N * 4);
    int* row_ptr  = (int*)alloc((size_t)(N + 1) * 4);
    int* cnt      = (int*)alloc((size_t)N * 4);
    int* bsums    = (int*)alloc((size_t)256 * 4);
    int* t_sorted = (int*)alloc((size_t)E * 4);

    // CSR build
    hipMemsetAsync(cnt, 0, (size_t)N * 4, stream);
    k_count<<<(E + 255) / 256, 256, 0, stream>>>(s, cnt, E);
    k_scan1<<<G, 256, 0, stream>>>(cnt, bsums, N);
    k_scan2<<<1, 256, 0, stream>>>(bsums, G);
    k_scan3<<<G, 256, 0, stream>>>(cnt, bsums, row_ptr, N);
    hipMemsetAsync(cnt, 0, (size_t)N * 4, stream);
    k_scatter<<<(E + 255) / 256, 256, 0, stream>>>(s, t, row_ptr, cnt, t_sorted, E);

    // W splits for hop weights
    k_wsplit<<<(10 * 128 * 128 + 255) / 256, 256, 0, stream>>>(fcsW, Whi, Wlo, 10 * 128 * 128);

    // fc1 + relu -> split planes (MFMA, 3-term)
    k_mmfc<1><<<NB, 256, 0, stream>>>(x_in, nullptr, fc1W, fc1b,
                                      nullptr, xbuf_hi, xbuf_lo, N);

    // hops
    for (int i = 0; i < 10; ++i) {
        const unsigned short* Wh = Whi + (size_t)i * 128 * 128;
        const unsigned short* Wl = Wlo + (size_t)i * 128 * 128;
        const float* b   = fcsb + (size_t)i * 128;
        const float* a1i = a1 + (size_t)i * 128;
        const float* a2i = a2 + (size_t)i * 128;
        if (i == 0) {
            // h == x at hop 0: H path redundant (hlin == xnew, h1a == xa2a)
            k_mm_bf<<<NB, 256, 0, stream>>>(xbuf_hi, xbuf_lo, NB, h_hi,
                                            Wh, Wl, b, xnb, hbf, N,
                                            a1i, x1a, a2i, xa2a, a2i, h1a);
            k_agg<<<(N + 3) / 4, 256, 0, stream>>>(xnb, xnb, x1a, xa2a, xa2a,
                                                   row_ptr, t_sorted, h_hi, h_lo, N);
        } else {
            k_mm_bf<<<2 * NB, 256, 0, stream>>>(xbuf_hi, xbuf_lo, NB, h_hi,
                                                Wh, Wl, b, xnb, hbf, N,
                                                a1i, x1a, a2i, xa2a, a2i, h1a);
            k_agg<<<(N + 3) / 4, 256, 0, stream>>>(xnb, hbf, x1a, xa2a, h1a,
                                                   row_ptr, t_sorted, h_hi, h_lo, N);
        }
    }

    // fc2 (MFMA, 2-term from h_hi, fp32 out)
    k_mmfc<2><<<NB, 256, 0, stream>>>(nullptr, h_hi, fc2W, fc2b,
                                      (float*)d_out, nullptr, nullptr, N);
}

// Round 8
// 879.411 us; speedup vs baseline: 1.3376x; 1.3376x over previous
//
#include <hip/hip_runtime.h>
#include <math.h>

// ---------------------------------------------------------------------------
// GTAN2 R8: k_mm_bf v3 — W (both bf16 planes) staged in LDS ONCE (64 KB, one
// barrier), X streamed per-lane directly from global: ZERO barriers in the
// k-loop (kills the barrier-serialized latency chain of R5-R7). Issue-early
// prefetch reverted everywhere (3x proven loser). h_lo plane removed (dead:
// H path and fc2 consume h_hi only). Hop-0 H-path elision kept.
// ---------------------------------------------------------------------------

typedef __attribute__((ext_vector_type(8))) short short8;
typedef __attribute__((ext_vector_type(4))) float f32x4;
#define MFMA16 __builtin_amdgcn_mfma_f32_16x16x32_bf16

__device__ __forceinline__ float lrelu02(float v) { return v > 0.f ? v : 0.2f * v; }

__device__ __forceinline__ float2 bf2f2(unsigned int v) {
    return make_float2(__uint_as_float(v << 16), __uint_as_float(v & 0xffff0000u));
}
__device__ __forceinline__ unsigned int f2bf(float f) {  // RNE bf16
    unsigned int u = __float_as_uint(f);
    u += 0x7fffu + ((u >> 16) & 1u);
    return u >> 16;
}
__device__ __forceinline__ float hi_part(float f) {
    return __uint_as_float(__float_as_uint(f) & 0xffff0000u);
}
__device__ __forceinline__ uint4 pack_hi(const float4& a, const float4& b) {
    uint4 r;
    r.x = (__float_as_uint(a.x) >> 16) | (__float_as_uint(a.y) & 0xffff0000u);
    r.y = (__float_as_uint(a.z) >> 16) | (__float_as_uint(a.w) & 0xffff0000u);
    r.z = (__float_as_uint(b.x) >> 16) | (__float_as_uint(b.y) & 0xffff0000u);
    r.w = (__float_as_uint(b.z) >> 16) | (__float_as_uint(b.w) & 0xffff0000u);
    return r;
}
__device__ __forceinline__ uint4 pack_lo(const float4& a, const float4& b) {
    uint4 r;
    r.x = f2bf(a.x - hi_part(a.x)) | (f2bf(a.y - hi_part(a.y)) << 16);
    r.y = f2bf(a.z - hi_part(a.z)) | (f2bf(a.w - hi_part(a.w)) << 16);
    r.z = f2bf(b.x - hi_part(b.x)) | (f2bf(b.y - hi_part(b.y)) << 16);
    r.w = f2bf(b.z - hi_part(b.z)) | (f2bf(b.w - hi_part(b.w)) << 16);
    return r;
}

// ---------------- CSR build ----------------
__global__ __launch_bounds__(256) void k_count(const int* __restrict__ s, int* __restrict__ cnt, int E) {
    int e = blockIdx.x * 256 + threadIdx.x;
    if (e < E) atomicAdd(&cnt[s[e]], 1);
}

__global__ __launch_bounds__(256) void k_scan1(const int* __restrict__ cnt, int* __restrict__ bs, int N) {
    __shared__ int sh[256];
    int idx = blockIdx.x * 256 + threadIdx.x;
    sh[threadIdx.x] = (idx < N) ? cnt[idx] : 0;
    __syncthreads();
#pragma unroll
    for (int off = 128; off; off >>= 1) {
        if (threadIdx.x < off) sh[threadIdx.x] += sh[threadIdx.x + off];
        __syncthreads();
    }
    if (threadIdx.x == 0) bs[blockIdx.x] = sh[0];
}

__global__ __launch_bounds__(256) void k_scan2(int* __restrict__ bs, int G) {
    __shared__ int sh[256];
    int t = threadIdx.x;
    int v = (t < G) ? bs[t] : 0;
    sh[t] = v;
    __syncthreads();
    int val = v;
#pragma unroll
    for (int off = 1; off < 256; off <<= 1) {
        int o = (t >= off) ? sh[t - off] : 0;
        __syncthreads();
        val += o; sh[t] = val;
        __syncthreads();
    }
    if (t < G) bs[t] = val - v;  // exclusive
}

__global__ __launch_bounds__(256) void k_scan3(const int* __restrict__ cnt, const int* __restrict__ bs,
                                               int* __restrict__ rp, int N) {
    __shared__ int sh[256];
    int t = threadIdx.x;
    int idx = blockIdx.x * 256 + t;
    int v = (idx < N) ? cnt[idx] : 0;
    sh[t] = v;
    __syncthreads();
    int val = v;
#pragma unroll
    for (int off = 1; off < 256; off <<= 1) {
        int o = (t >= off) ? sh[t - off] : 0;
        __syncthreads();
        val += o; sh[t] = val;
        __syncthreads();
    }
    if (idx <= N) rp[idx] = val - v + bs[blockIdx.x];
}

__global__ __launch_bounds__(256) void k_scatter(const int* __restrict__ s, const int* __restrict__ t,
                                                 const int* __restrict__ rp, int* __restrict__ cursor,
                                                 int* __restrict__ t_sorted, int E) {
    int e = blockIdx.x * 256 + threadIdx.x;
    if (e < E) {
        int u = s[e];
        int pos = atomicAdd(&cursor[u], 1);
        t_sorted[rp[u] + pos] = t[e];
    }
}

// ---------------- W split for hop weights ----------------
__global__ __launch_bounds__(256) void k_wsplit(const float* __restrict__ W,
                                                unsigned short* __restrict__ Whi,
                                                unsigned short* __restrict__ Wlo, int total) {
    int i = blockIdx.x * 256 + threadIdx.x;
    if (i < total) {
        float f = W[i];
        unsigned int u = __float_as_uint(f);
        Whi[i] = (unsigned short)(u >> 16);
        Wlo[i] = (unsigned short)f2bf(f - __uint_as_float(u & 0xffff0000u));
    }
}

// ---------------- fc1/fc2 MFMA GEMM (R6-style per-kc staging) ----------------
// MODE 1 = fc1: fp32 X [N,256] & fp32 W [128,256], 3-term, relu, split out.
// MODE 2 = fc2: bf16 X [N,128] (h_hi) & fp32 W [64,128], 2-term, fp32 out.
template <int MODE>
__global__ __launch_bounds__(256) void k_mmfc(
    const float* __restrict__ Xf,
    const unsigned short* __restrict__ Xhi,
    const float* __restrict__ Wf, const float* __restrict__ bias,
    float* __restrict__ Yf, unsigned short* __restrict__ Yhi, unsigned short* __restrict__ Ylo,
    int N) {
    constexpr int K = (MODE == 1) ? 256 : 128;
    constexpr int NCOLS = (MODE == 1) ? 128 : 64;
    __shared__ unsigned short lds[2 * 128 * 64];  // 32 KB
    unsigned short* Xs = lds;
    unsigned short* Wt = lds + 128 * 64;

    const int tid = threadIdx.x;
    const int r0 = blockIdx.x * 128;
    const int srow = tid & 127;
    const int sp = tid >> 7;
    const int xrow = r0 + srow;
    const bool xok = xrow < N;
    const bool wok = srow < NCOLS;

    const int lane = tid & 63;
    const int w = tid >> 6;
    const int wr = (w >> 1) * 64, wc = (w & 1) * 64;
    const int frow = lane & 15;
    const int fk = lane >> 4;
    const int q4 = lane >> 4;

    f32x4 acc[4][4];
#pragma unroll
    for (int i = 0; i < 4; ++i)
#pragma unroll
        for (int j = 0; j < 4; ++j) acc[i][j] = (f32x4){0.f, 0.f, 0.f, 0.f};

    const float4 z4 = make_float4(0.f, 0.f, 0.f, 0.f);
    const uint4 zz = make_uint4(0, 0, 0, 0);

    for (int kc = 0; kc < K / 32; ++kc) {
        if constexpr (MODE == 1) {
            const float* xp = Xf + (size_t)xrow * K + kc * 32 + sp * 16;
            const float* wp = Wf + (size_t)srow * K + kc * 32 + sp * 16;
            float4 xv[4], wv[4];
#pragma unroll
            for (int q = 0; q < 4; ++q) {
                xv[q] = xok ? *(const float4*)(xp + q * 4) : z4;
                wv[q] = wok ? *(const float4*)(wp + q * 4) : z4;
            }
            __syncthreads();
#pragma unroll
            for (int j = 0; j < 2; ++j) {
                int g = sp * 2 + j;
                *(uint4*)(Xs + srow * 64 + ((g) ^ (srow & 7)) * 8)     = pack_hi(xv[2 * j], xv[2 * j + 1]);
                *(uint4*)(Xs + srow * 64 + ((4 | g) ^ (srow & 7)) * 8) = pack_lo(xv[2 * j], xv[2 * j + 1]);
                *(uint4*)(Wt + srow * 64 + ((g) ^ (srow & 7)) * 8)     = pack_hi(wv[2 * j], wv[2 * j + 1]);
                *(uint4*)(Wt + srow * 64 + ((4 | g) ^ (srow & 7)) * 8) = pack_lo(wv[2 * j], wv[2 * j + 1]);
            }
            __syncthreads();
        } else {
            const unsigned short* xp = Xhi + (size_t)xrow * K + kc * 32;
            const float* wp = Wf + (size_t)srow * K + kc * 32 + sp * 16;
            uint4 xg[4];
            float4 wv[4];
#pragma unroll
            for (int g = 0; g < 4; ++g) xg[g] = (xok && sp == 0) ? ((const uint4*)xp)[g] : zz;
#pragma unroll
            for (int q = 0; q < 4; ++q) wv[q] = wok ? *(const float4*)(wp + q * 4) : z4;
            __syncthreads();
            if (sp == 0) {
#pragma unroll
                for (int g = 0; g < 4; ++g) {
                    int p = g ^ (srow & 7);
                    *(uint4*)(Xs + srow * 64 + p * 8) = xg[g];
                }
            }
#pragma unroll
            for (int j = 0; j < 2; ++j) {
                int g = sp * 2 + j;
                *(uint4*)(Wt + srow * 64 + ((g) ^ (srow & 7)) * 8)     = pack_hi(wv[2 * j], wv[2 * j + 1]);
                *(uint4*)(Wt + srow * 64 + ((4 | g) ^ (srow & 7)) * 8) = pack_lo(wv[2 * j], wv[2 * j + 1]);
            }
            __syncthreads();
        }

        short8 ah[4], bh[4], bl[4];
#pragma unroll
        for (int ri = 0; ri < 4; ++ri) {
            int row = wr + ri * 16 + frow;
            ah[ri] = *(const short8*)(Xs + row * 64 + ((fk) ^ (row & 7)) * 8);
        }
#pragma unroll
        for (int ci = 0; ci < 4; ++ci) {
            int col = wc + ci * 16 + frow;
            bh[ci] = *(const short8*)(Wt + col * 64 + ((fk) ^ (col & 7)) * 8);
            bl[ci] = *(const short8*)(Wt + col * 64 + ((4 | fk) ^ (col & 7)) * 8);
        }
        if constexpr (MODE == 1) {
            short8 al[4];
#pragma unroll
            for (int ri = 0; ri < 4; ++ri) {
                int row = wr + ri * 16 + frow;
                al[ri] = *(const short8*)(Xs + row * 64 + ((4 | fk) ^ (row & 7)) * 8);
            }
#pragma unroll
            for (int ri = 0; ri < 4; ++ri)
#pragma unroll
                for (int ci = 0; ci < 4; ++ci) {
                    acc[ri][ci] = MFMA16(ah[ri], bh[ci], acc[ri][ci], 0, 0, 0);
                    acc[ri][ci] = MFMA16(ah[ri], bl[ci], acc[ri][ci], 0, 0, 0);
                    acc[ri][ci] = MFMA16(al[ri], bh[ci], acc[ri][ci], 0, 0, 0);
                }
        } else {
#pragma unroll
            for (int ri = 0; ri < 4; ++ri)
#pragma unroll
                for (int ci = 0; ci < 4; ++ci) {
                    acc[ri][ci] = MFMA16(ah[ri], bh[ci], acc[ri][ci], 0, 0, 0);
                    acc[ri][ci] = MFMA16(ah[ri], bl[ci], acc[ri][ci], 0, 0, 0);
                }
        }
    }

#pragma unroll
    for (int ci = 0; ci < 4; ++ci) {
        int col = wc + ci * 16 + frow;
        float bcol = (col < NCOLS) ? bias[col] : 0.f;
#pragma unroll
        for (int ri = 0; ri < 4; ++ri) {
            f32x4 v = acc[ri][ci];
#pragma unroll
            for (int reg = 0; reg < 4; ++reg) {
                int grow = r0 + wr + ri * 16 + q4 * 4 + reg;
                float val = v[reg] + bcol;
                if (grow < N && col < NCOLS) {
                    if constexpr (MODE == 1) {
                        val = fmaxf(val, 0.f);
                        Yhi[(size_t)grow * 128 + col] = (unsigned short)(__float_as_uint(val) >> 16);
                        Ylo[(size_t)grow * 128 + col] = (unsigned short)f2bf(val - hi_part(val));
                    } else {
                        Yf[(size_t)grow * 64 + col] = val;
                    }
                }
            }
        }
    }
}

// ---------------- hop GEMM v3: W-in-LDS-once, barrier-free X streaming ------
// X path (blocks < nblk0): 3-term (Xhi,Xlo) -> xnb bf16 + dots(a1,a2).
// H path: 2-term (Hhi) -> hbf bf16 + dot(a2).
__global__ __launch_bounds__(256) void k_mm_bf(
    const unsigned short* __restrict__ Xhi0, const unsigned short* __restrict__ Xlo0, int nblk0,
    const unsigned short* __restrict__ Hhi1,
    const unsigned short* __restrict__ Whi, const unsigned short* __restrict__ Wlo,
    const float* __restrict__ bias,
    unsigned short* __restrict__ Yb0, unsigned short* __restrict__ Yb1, int N,
    const float* __restrict__ dA0, float* __restrict__ oA0,
    const float* __restrict__ dB0, float* __restrict__ oB0,
    const float* __restrict__ dA1, float* __restrict__ oA1) {
    // LDS: W hi plane [0,16384), W lo plane [16384,32768) (ushort idx).
    // Per plane: col-major rows of 128 elems, granule-swizzled g^=(col&7).
    // Epilogue reuses [0,16384) as So (bf16 C tile) + dotbuf at +16384.
    __shared__ unsigned short lds[2 * 128 * 128];  // 64 KB

    const int tid = threadIdx.x;
    const bool second = (int)blockIdx.x >= nblk0;
    const int bx = second ? (int)blockIdx.x - nblk0 : (int)blockIdx.x;
    const int r0 = bx * 128;

    // ---- stage both W planes once ----
    {
        int col = tid & 127;
        int pl = tid >> 7;
        const unsigned short* wp = (pl ? Wlo : Whi) + (size_t)col * 128;
        unsigned short* dst = lds + pl * 16384 + col * 128;
#pragma unroll
        for (int g = 0; g < 16; ++g)
            *(uint4*)(dst + ((g ^ (col & 7)) * 8)) = ((const uint4*)wp)[g];
    }
    __syncthreads();

    const int lane = tid & 63;
    const int w = tid >> 6;
    const int wr = (w >> 1) * 64, wc = (w & 1) * 64;
    const int frow = lane & 15;
    const int fk = lane >> 4;
    const int q4 = lane >> 4;

    const unsigned short* Xh = second ? Hhi1 : Xhi0;
    const unsigned short* Xl = Xlo0;  // used only when !second
    unsigned short* Yb = second ? Yb1 : Yb0;

    f32x4 acc[4][4];
#pragma unroll
    for (int i = 0; i < 4; ++i)
#pragma unroll
        for (int j = 0; j < 4; ++j) acc[i][j] = (f32x4){0.f, 0.f, 0.f, 0.f};

    const short8 z8 = (short8){0, 0, 0, 0, 0, 0, 0, 0};

    // ---- barrier-free k-loop: X frags from global, B frags from LDS ----
#pragma unroll
    for (int kc = 0; kc < 4; ++kc) {
        short8 ah[4], al[4], bh[4], bl[4];
#pragma unroll
        for (int ri = 0; ri < 4; ++ri) {
            int row = r0 + wr + ri * 16 + frow;
            bool ok = row < N;
            const unsigned short* ph = Xh + (size_t)row * 128 + kc * 32 + fk * 8;
            ah[ri] = ok ? *(const short8*)ph : z8;
            if (!second) {
                const unsigned short* pl = Xl + (size_t)row * 128 + kc * 32 + fk * 8;
                al[ri] = ok ? *(const short8*)pl : z8;
            }
        }
#pragma unroll
        for (int ci = 0; ci < 4; ++ci) {
            int col = wc + ci * 16 + frow;
            int g = kc * 4 + fk;
            int go = (g ^ (col & 7)) * 8;
            bh[ci] = *(const short8*)(lds + col * 128 + go);
            bl[ci] = *(const short8*)(lds + 16384 + col * 128 + go);
        }
        if (!second) {
#pragma unroll
            for (int ri = 0; ri < 4; ++ri)
#pragma unroll
                for (int ci = 0; ci < 4; ++ci) {
                    acc[ri][ci] = MFMA16(ah[ri], bh[ci], acc[ri][ci], 0, 0, 0);
                    acc[ri][ci] = MFMA16(ah[ri], bl[ci], acc[ri][ci], 0, 0, 0);
                    acc[ri][ci] = MFMA16(al[ri], bh[ci], acc[ri][ci], 0, 0, 0);
                }
        } else {
#pragma unroll
            for (int ri = 0; ri < 4; ++ri)
#pragma unroll
                for (int ci = 0; ci < 4; ++ci) {
                    acc[ri][ci] = MFMA16(ah[ri], bh[ci], acc[ri][ci], 0, 0, 0);
                    acc[ri][ci] = MFMA16(ah[ri], bl[ci], acc[ri][ci], 0, 0, 0);
                }
        }
    }

    // ---- epilogue: bias + dots + bf16 LDS staging + dense stores ----
    const float* dA = second ? dA1 : dA0;
    const float* dB = second ? nullptr : dB0;
    unsigned short* So = lds;                       // [128][128] bf16, swizzled
    float* dotbuf = (float*)(lds + 16384);          // 2 KB

    float dotA[4][4] = {}, dotB[4][4] = {};
    __syncthreads();  // all waves done reading W planes
#pragma unroll
    for (int ci = 0; ci < 4; ++ci) {
        int col = wc + ci * 16 + frow;
        float bcol = bias[col];
        float dAc = dA ? dA[col] : 0.f;
        float dBc = dB ? dB[col] : 0.f;
#pragma unroll
        for (int ri = 0; ri < 4; ++ri) {
            f32x4 v = acc[ri][ci];
#pragma unroll
            for (int reg = 0; reg < 4; ++reg) {
                float val = v[reg] + bcol;
                int row = wr + ri * 16 + q4 * 4 + reg;
                int dw = (col >> 1) ^ ((row & 12) << 1);
                So[row * 128 + dw * 2 + (col & 1)] = (unsigned short)f2bf(val);
                dotA[ri][reg] = fmaf(val, dAc, dotA[ri][reg]);
                dotB[ri][reg] = fmaf(val, dBc, dotB[ri][reg]);
            }
        }
    }
#pragma unroll
    for (int m = 1; m < 16; m <<= 1)
#pragma unroll
        for (int ri = 0; ri < 4; ++ri)
#pragma unroll
            for (int reg = 0; reg < 4; ++reg) {
                dotA[ri][reg] += __shfl_xor(dotA[ri][reg], m, 64);
                dotB[ri][reg] += __shfl_xor(dotB[ri][reg], m, 64);
            }
    if (frow == 0) {
#pragma unroll
        for (int ri = 0; ri < 4; ++ri)
#pragma unroll
            for (int reg = 0; reg < 4; ++reg) {
                int rl = wr + ri * 16 + q4 * 4 + reg;
                dotbuf[(0 * 128 + rl) * 2 + (w & 1)] = dotA[ri][reg];
                dotbuf[(1 * 128 + rl) * 2 + (w & 1)] = dotB[ri][reg];
            }
    }
    __syncthreads();

#pragma unroll
    for (int q = 0; q < 8; ++q) {
        int idx = q * 256 + tid;        // 0..2047
        int row = idx >> 4;
        int gc = idx & 15;
        int dwb = (gc * 4) ^ ((row & 12) << 1);
        uint4 vv = *(const uint4*)(So + row * 128 + dwb * 2);
        int grow = r0 + row;
        if (grow < N) *(uint4*)(Yb + (size_t)grow * 128 + gc * 8) = vv;
    }
    {
        int d = tid >> 7, rl = tid & 127;
        int grow = r0 + rl;
        float* oA = second ? oA1 : oA0;
        float* oB = second ? nullptr : oB0;
        if (grow < N) {
            float v = dotbuf[(d * 128 + rl) * 2] + dotbuf[(d * 128 + rl) * 2 + 1];
            if (d == 0) { if (oA) oA[grow] = v; }
            else        { if (oB) oB[grow] = v; }
        }
    }
}

// ---------------- aggregation: LDS-staged (t,w), 8-deep gather groups --------
__global__ __launch_bounds__(256) void k_agg(
    const unsigned short* __restrict__ xnb, const unsigned short* __restrict__ hbf,
    const float* __restrict__ x1a, const float* __restrict__ xa2a,
    const float* __restrict__ h1a, const int* __restrict__ rp,
    const int* __restrict__ ts,
    unsigned short* __restrict__ hhi, int N) {
    __shared__ uint2 ew[4][64];
    const int wid = threadIdx.x >> 6;
    const int lane = threadIdx.x & 63;
    const int u = blockIdx.x * 4 + wid;
    if (u >= N) return;  // wave-uniform; per-wave LDS slice only
    const int l2 = lane << 1;
    float x1u = x1a[u];
    float w2 = expf(lrelu02(x1u + xa2a[u]));
    float2 xr = bf2f2(*(const unsigned int*)(xnb + (size_t)u * 128 + l2));
    float accx = w2 * xr.x, accy = w2 * xr.y;
    float div = w2;
    int p0 = rp[u], p1 = rp[u + 1];
    for (int base = p0; base < p1; base += 64) {
        int e = base + lane;
        uint2 pk = make_uint2(0u, 0u);
        if (e < p1) {
            int tv = ts[e];
            pk.x = (unsigned int)tv;
            pk.y = __float_as_uint(expf(lrelu02(x1u + h1a[tv])));
        }
        ew[wid][lane] = pk;
        int m = p1 - base; if (m > 64) m = 64;
        int m8 = (m + 7) & ~7;
        for (int j = 0; j < m8; j += 8) {
            uint2 q[8];
#pragma unroll
            for (int k = 0; k < 8; ++k) q[k] = ew[wid][j + k];
            unsigned int hv[8];
#pragma unroll
            for (int k = 0; k < 8; ++k)
                hv[k] = *(const unsigned int*)(hbf + (size_t)q[k].x * 128 + l2);
#pragma unroll
            for (int k = 0; k < 8; ++k) {
                float ww = __uint_as_float(q[k].y);
                float2 f = bf2f2(hv[k]);
                accx = fmaf(ww, f.x, accx);
                accy = fmaf(ww, f.y, accy);
                div += ww;
            }
        }
    }
    float ox = accx / div, oy = accy / div;
    ox = ox > 0.f ? ox : expf(ox) - 1.f;
    oy = oy > 0.f ? oy : expf(oy) - 1.f;
    unsigned int hx = __float_as_uint(ox), hy = __float_as_uint(oy);
    *(unsigned int*)(hhi + (size_t)u * 128 + l2) = (hx >> 16) | (hy & 0xffff0000u);
}

// ---------------- launch ----------------
extern "C" void kernel_launch(void* const* d_in, const int* in_sizes, int n_in,
                              void* d_out, int out_size, void* d_ws, size_t ws_size,
                              hipStream_t stream) {
    const float* x_in = (const float*)d_in[0];
    const int*   s    = (const int*)d_in[1];
    const int*   t    = (const int*)d_in[2];
    const float* fc1W = (const float*)d_in[3];
    const float* fc1b = (const float*)d_in[4];
    const float* fcsW = (const float*)d_in[5];
    const float* fcsb = (const float*)d_in[6];
    const float* a1   = (const float*)d_in[7];
    const float* a2   = (const float*)d_in[8];
    const float* fc2W = (const float*)d_in[9];
    const float* fc2b = (const float*)d_in[10];

    const int N = in_sizes[0] / 256;  // 50000
    const int E = in_sizes[1];        // 800000
    const int G = (N + 255) / 256;
    const int NB = (N + 127) / 128;   // 391

    char* ws = (char*)d_ws;
    size_t off = 0;
    auto alloc = [&](size_t bytes) -> void* {
        void* p = ws + off;
        off += (bytes + 255) & ~(size_t)255;
        return p;
    };
    unsigned short* xbuf_hi = (unsigned short*)alloc((size_t)N * 128 * 2);
    unsigned short* xbuf_lo = (unsigned short*)alloc((size_t)N * 128 * 2);
    unsigned short* h_hi    = (unsigned short*)alloc((size_t)N * 128 * 2);
    unsigned short* xnb     = (unsigned short*)alloc((size_t)N * 128 * 2);
    unsigned short* hbf     = (unsigned short*)alloc((size_t)N * 128 * 2);
    unsigned short* Whi = (unsigned short*)alloc((size_t)10 * 128 * 128 * 2);
    unsigned short* Wlo = (unsigned short*)alloc((size_t)10 * 128 * 128 * 2);
    float* x1a  = (float*)alloc((size_t)N * 4);
    float* xa2a = (float*)alloc((size_t)N * 4);
    float* h1a  = (float*)alloc((size_t)N * 4);
    int* row_ptr  = (int*)alloc((size_t)(N + 1) * 4);
    int* cnt      = (int*)alloc((size_t)N * 4);
    int* bsums    = (int*)alloc((size_t)256 * 4);
    int* t_sorted = (int*)alloc((size_t)E * 4);

    // CSR build
    hipMemsetAsync(cnt, 0, (size_t)N * 4, stream);
    k_count<<<(E + 255) / 256, 256, 0, stream>>>(s, cnt, E);
    k_scan1<<<G, 256, 0, stream>>>(cnt, bsums, N);
    k_scan2<<<1, 256, 0, stream>>>(bsums, G);
    k_scan3<<<G, 256, 0, stream>>>(cnt, bsums, row_ptr, N);
    hipMemsetAsync(cnt, 0, (size_t)N * 4, stream);
    k_scatter<<<(E + 255) / 256, 256, 0, stream>>>(s, t, row_ptr, cnt, t_sorted, E);

    // W splits for hop weights
    k_wsplit<<<(10 * 128 * 128 + 255) / 256, 256, 0, stream>>>(fcsW, Whi, Wlo, 10 * 128 * 128);

    // fc1 + relu -> split planes
    k_mmfc<1><<<NB, 256, 0, stream>>>(x_in, nullptr, fc1W, fc1b,
                                      nullptr, xbuf_hi, xbuf_lo, N);

    // hops
    for (int i = 0; i < 10; ++i) {
        const unsigned short* Wh = Whi + (size_t)i * 128 * 128;
        const unsigned short* Wl = Wlo + (size_t)i * 128 * 128;
        const float* b   = fcsb + (size_t)i * 128;
        const float* a1i = a1 + (size_t)i * 128;
        const float* a2i = a2 + (size_t)i * 128;
        if (i == 0) {
            // h == x at hop 0: H path redundant (hlin == xnew, h1a == xa2a)
            k_mm_bf<<<NB, 256, 0, stream>>>(xbuf_hi, xbuf_lo, NB, h_hi,
                                            Wh, Wl, b, xnb, hbf, N,
                                            a1i, x1a, a2i, xa2a, a2i, h1a);
            k_agg<<<(N + 3) / 4, 256, 0, stream>>>(xnb, xnb, x1a, xa2a, xa2a,
                                                   row_ptr, t_sorted, h_hi, N);
        } else {
            k_mm_bf<<<2 * NB, 256, 0, stream>>>(xbuf_hi, xbuf_lo, NB, h_hi,
                                                Wh, Wl, b, xnb, hbf, N,
                                                a1i, x1a, a2i, xa2a, a2i, h1a);
            k_agg<<<(N + 3) / 4, 256, 0, stream>>>(xnb, hbf, x1a, xa2a, h1a,
                                                   row_ptr, t_sorted, h_hi, N);
        }
    }

    // fc2 (2-term from h_hi, fp32 out)
    k_mmfc<2><<<NB, 256, 0, stream>>>(nullptr, h_hi, fc2W, fc2b,
                                      (float*)d_out, nullptr, nullptr, N);
}

// Round 9
// 859.511 us; speedup vs baseline: 1.3686x; 1.0232x over previous
//
#include <hip/hip_runtime.h>
#include <math.h>

// ---------------------------------------------------------------------------
// GTAN2 R9: fc1/fc2 rebuilt barrier-free (zero LDS, zero syncthreads): all
// fragments straight from global; fp32 X converted to hi/lo bf16 in-register;
// W pre-split to bf16 planes by k_wsplit. fc2 fixes the half-wasted-wave
// layout (BM=64, all waves on cols 0-63). k_mm_bf/k_agg/CSR unchanged (R8).
// ---------------------------------------------------------------------------

typedef __attribute__((ext_vector_type(8))) short short8;
typedef __attribute__((ext_vector_type(4))) float f32x4;
#define MFMA16 __builtin_amdgcn_mfma_f32_16x16x32_bf16

__device__ __forceinline__ float lrelu02(float v) { return v > 0.f ? v : 0.2f * v; }

__device__ __forceinline__ float2 bf2f2(unsigned int v) {
    return make_float2(__uint_as_float(v << 16), __uint_as_float(v & 0xffff0000u));
}
__device__ __forceinline__ unsigned int f2bf(float f) {  // RNE bf16
    unsigned int u = __float_as_uint(f);
    u += 0x7fffu + ((u >> 16) & 1u);
    return u >> 16;
}
__device__ __forceinline__ float hi_part(float f) {
    return __uint_as_float(__float_as_uint(f) & 0xffff0000u);
}
__device__ __forceinline__ uint4 pack_hi(const float4& a, const float4& b) {
    uint4 r;
    r.x = (__float_as_uint(a.x) >> 16) | (__float_as_uint(a.y) & 0xffff0000u);
    r.y = (__float_as_uint(a.z) >> 16) | (__float_as_uint(a.w) & 0xffff0000u);
    r.z = (__float_as_uint(b.x) >> 16) | (__float_as_uint(b.y) & 0xffff0000u);
    r.w = (__float_as_uint(b.z) >> 16) | (__float_as_uint(b.w) & 0xffff0000u);
    return r;
}
__device__ __forceinline__ uint4 pack_lo(const float4& a, const float4& b) {
    uint4 r;
    r.x = f2bf(a.x - hi_part(a.x)) | (f2bf(a.y - hi_part(a.y)) << 16);
    r.y = f2bf(a.z - hi_part(a.z)) | (f2bf(a.w - hi_part(a.w)) << 16);
    r.z = f2bf(b.x - hi_part(b.x)) | (f2bf(b.y - hi_part(b.y)) << 16);
    r.w = f2bf(b.z - hi_part(b.z)) | (f2bf(b.w - hi_part(b.w)) << 16);
    return r;
}

// ---------------- CSR build ----------------
__global__ __launch_bounds__(256) void k_count(const int* __restrict__ s, int* __restrict__ cnt, int E) {
    int e = blockIdx.x * 256 + threadIdx.x;
    if (e < E) atomicAdd(&cnt[s[e]], 1);
}

__global__ __launch_bounds__(256) void k_scan1(const int* __restrict__ cnt, int* __restrict__ bs, int N) {
    __shared__ int sh[256];
    int idx = blockIdx.x * 256 + threadIdx.x;
    sh[threadIdx.x] = (idx < N) ? cnt[idx] : 0;
    __syncthreads();
#pragma unroll
    for (int off = 128; off; off >>= 1) {
        if (threadIdx.x < off) sh[threadIdx.x] += sh[threadIdx.x + off];
        __syncthreads();
    }
    if (threadIdx.x == 0) bs[blockIdx.x] = sh[0];
}

__global__ __launch_bounds__(256) void k_scan2(int* __restrict__ bs, int G) {
    __shared__ int sh[256];
    int t = threadIdx.x;
    int v = (t < G) ? bs[t] : 0;
    sh[t] = v;
    __syncthreads();
    int val = v;
#pragma unroll
    for (int off = 1; off < 256; off <<= 1) {
        int o = (t >= off) ? sh[t - off] : 0;
        __syncthreads();
        val += o; sh[t] = val;
        __syncthreads();
    }
    if (t < G) bs[t] = val - v;  // exclusive
}

__global__ __launch_bounds__(256) void k_scan3(const int* __restrict__ cnt, const int* __restrict__ bs,
                                               int* __restrict__ rp, int N) {
    __shared__ int sh[256];
    int t = threadIdx.x;
    int idx = blockIdx.x * 256 + t;
    int v = (idx < N) ? cnt[idx] : 0;
    sh[t] = v;
    __syncthreads();
    int val = v;
#pragma unroll
    for (int off = 1; off < 256; off <<= 1) {
        int o = (t >= off) ? sh[t - off] : 0;
        __syncthreads();
        val += o; sh[t] = val;
        __syncthreads();
    }
    if (idx <= N) rp[idx] = val - v + bs[blockIdx.x];
}

__global__ __launch_bounds__(256) void k_scatter(const int* __restrict__ s, const int* __restrict__ t,
                                                 const int* __restrict__ rp, int* __restrict__ cursor,
                                                 int* __restrict__ t_sorted, int E) {
    int e = blockIdx.x * 256 + threadIdx.x;
    if (e < E) {
        int u = s[e];
        int pos = atomicAdd(&cursor[u], 1);
        t_sorted[rp[u] + pos] = t[e];
    }
}

// ---------------- W split ----------------
__global__ __launch_bounds__(256) void k_wsplit(const float* __restrict__ W,
                                                unsigned short* __restrict__ Whi,
                                                unsigned short* __restrict__ Wlo, int total) {
    int i = blockIdx.x * 256 + threadIdx.x;
    if (i < total) {
        float f = W[i];
        unsigned int u = __float_as_uint(f);
        Whi[i] = (unsigned short)(u >> 16);
        Wlo[i] = (unsigned short)f2bf(f - __uint_as_float(u & 0xffff0000u));
    }
}

// ---------------- fc1: barrier-free, zero-LDS, 3-term ----------------
// X fp32 [N,256] converted in-register; W planes bf16 [128,256]; relu; split out.
__global__ __launch_bounds__(256) void k_fc1(
    const float* __restrict__ Xf,
    const unsigned short* __restrict__ Wh, const unsigned short* __restrict__ Wl,
    const float* __restrict__ bias,
    unsigned short* __restrict__ Yhi, unsigned short* __restrict__ Ylo, int N) {
    const int tid = threadIdx.x;
    const int r0 = blockIdx.x * 128;
    const int lane = tid & 63;
    const int w = tid >> 6;
    const int wr = (w >> 1) * 64, wc = (w & 1) * 64;
    const int frow = lane & 15;
    const int fk = lane >> 4;
    const int q4 = lane >> 4;

    f32x4 acc[4][4];
#pragma unroll
    for (int i = 0; i < 4; ++i)
#pragma unroll
        for (int j = 0; j < 4; ++j) acc[i][j] = (f32x4){0.f, 0.f, 0.f, 0.f};

    const float4 z4 = make_float4(0.f, 0.f, 0.f, 0.f);
#pragma unroll
    for (int kc = 0; kc < 8; ++kc) {
        short8 ah[4], al[4];
#pragma unroll
        for (int ri = 0; ri < 4; ++ri) {
            int row = r0 + wr + ri * 16 + frow;
            float4 va = z4, vb = z4;
            if (row < N) {
                const float* p = Xf + (size_t)row * 256 + kc * 32 + fk * 8;
                va = *(const float4*)p;
                vb = *(const float4*)(p + 4);
            }
            uint4 h = pack_hi(va, vb);
            uint4 l = pack_lo(va, vb);
            ah[ri] = *(short8*)&h;
            al[ri] = *(short8*)&l;
        }
#pragma unroll
        for (int ci = 0; ci < 4; ++ci) {
            int col = wc + ci * 16 + frow;
            short8 bh = *(const short8*)(Wh + (size_t)col * 256 + kc * 32 + fk * 8);
            short8 bl = *(const short8*)(Wl + (size_t)col * 256 + kc * 32 + fk * 8);
#pragma unroll
            for (int ri = 0; ri < 4; ++ri) {
                acc[ri][ci] = MFMA16(ah[ri], bh, acc[ri][ci], 0, 0, 0);
                acc[ri][ci] = MFMA16(ah[ri], bl, acc[ri][ci], 0, 0, 0);
                acc[ri][ci] = MFMA16(al[ri], bh, acc[ri][ci], 0, 0, 0);
            }
        }
    }

#pragma unroll
    for (int ci = 0; ci < 4; ++ci) {
        int col = wc + ci * 16 + frow;
        float bcol = bias[col];
#pragma unroll
        for (int ri = 0; ri < 4; ++ri) {
            f32x4 v = acc[ri][ci];
#pragma unroll
            for (int reg = 0; reg < 4; ++reg) {
                int grow = r0 + wr + ri * 16 + q4 * 4 + reg;
                if (grow < N) {
                    float val = fmaxf(v[reg] + bcol, 0.f);
                    Yhi[(size_t)grow * 128 + col] = (unsigned short)(__float_as_uint(val) >> 16);
                    Ylo[(size_t)grow * 128 + col] = (unsigned short)f2bf(val - hi_part(val));
                }
            }
        }
    }
}

// ---------------- fc2: barrier-free, zero-LDS, 2-term, BM=64 ----------------
// X = h_hi bf16 [N,128]; W planes bf16 [64,128]; fp32 out [N,64].
__global__ __launch_bounds__(256) void k_fc2(
    const unsigned short* __restrict__ Xhi,
    const unsigned short* __restrict__ Wh, const unsigned short* __restrict__ Wl,
    const float* __restrict__ bias, float* __restrict__ Yf, int N) {
    const int tid = threadIdx.x;
    const int r0 = blockIdx.x * 64;
    const int lane = tid & 63;
    const int w = tid >> 6;
    const int wr = w * 16;
    const int frow = lane & 15;
    const int fk = lane >> 4;
    const int q4 = lane >> 4;

    f32x4 acc[4];
#pragma unroll
    for (int j = 0; j < 4; ++j) acc[j] = (f32x4){0.f, 0.f, 0.f, 0.f};

    const short8 z8 = (short8){0, 0, 0, 0, 0, 0, 0, 0};
#pragma unroll
    for (int kc = 0; kc < 4; ++kc) {
        int row = r0 + wr + frow;
        short8 ah = (row < N) ? *(const short8*)(Xhi + (size_t)row * 128 + kc * 32 + fk * 8) : z8;
#pragma unroll
        for (int ci = 0; ci < 4; ++ci) {
            int col = ci * 16 + frow;
            short8 bh = *(const short8*)(Wh + (size_t)col * 128 + kc * 32 + fk * 8);
            short8 bl = *(const short8*)(Wl + (size_t)col * 128 + kc * 32 + fk * 8);
            acc[ci] = MFMA16(ah, bh, acc[ci], 0, 0, 0);
            acc[ci] = MFMA16(ah, bl, acc[ci], 0, 0, 0);
        }
    }

#pragma unroll
    for (int ci = 0; ci < 4; ++ci) {
        int col = ci * 16 + frow;
        float bcol = bias[col];
#pragma unroll
        for (int reg = 0; reg < 4; ++reg) {
            int grow = r0 + wr + q4 * 4 + reg;
            if (grow < N) Yf[(size_t)grow * 64 + col] = acc[ci][reg] + bcol;
        }
    }
}

// ---------------- hop GEMM v3: W-in-LDS-once, barrier-free X streaming ------
__global__ __launch_bounds__(256) void k_mm_bf(
    const unsigned short* __restrict__ Xhi0, const unsigned short* __restrict__ Xlo0, int nblk0,
    const unsigned short* __restrict__ Hhi1,
    const unsigned short* __restrict__ Whi, const unsigned short* __restrict__ Wlo,
    const float* __restrict__ bias,
    unsigned short* __restrict__ Yb0, unsigned short* __restrict__ Yb1, int N,
    const float* __restrict__ dA0, float* __restrict__ oA0,
    const float* __restrict__ dB0, float* __restrict__ oB0,
    const float* __restrict__ dA1, float* __restrict__ oA1) {
    __shared__ unsigned short lds[2 * 128 * 128];  // 64 KB

    const int tid = threadIdx.x;
    const bool second = (int)blockIdx.x >= nblk0;
    const int bx = second ? (int)blockIdx.x - nblk0 : (int)blockIdx.x;
    const int r0 = bx * 128;

    {
        int col = tid & 127;
        int pl = tid >> 7;
        const unsigned short* wp = (pl ? Wlo : Whi) + (size_t)col * 128;
        unsigned short* dst = lds + pl * 16384 + col * 128;
#pragma unroll
        for (int g = 0; g < 16; ++g)
            *(uint4*)(dst + ((g ^ (col & 7)) * 8)) = ((const uint4*)wp)[g];
    }
    __syncthreads();

    const int lane = tid & 63;
    const int w = tid >> 6;
    const int wr = (w >> 1) * 64, wc = (w & 1) * 64;
    const int frow = lane & 15;
    const int fk = lane >> 4;
    const int q4 = lane >> 4;

    const unsigned short* Xh = second ? Hhi1 : Xhi0;
    const unsigned short* Xl = Xlo0;
    unsigned short* Yb = second ? Yb1 : Yb0;

    f32x4 acc[4][4];
#pragma unroll
    for (int i = 0; i < 4; ++i)
#pragma unroll
        for (int j = 0; j < 4; ++j) acc[i][j] = (f32x4){0.f, 0.f, 0.f, 0.f};

    const short8 z8 = (short8){0, 0, 0, 0, 0, 0, 0, 0};

#pragma unroll
    for (int kc = 0; kc < 4; ++kc) {
        short8 ah[4], al[4], bh[4], bl[4];
#pragma unroll
        for (int ri = 0; ri < 4; ++ri) {
            int row = r0 + wr + ri * 16 + frow;
            bool ok = row < N;
            const unsigned short* ph = Xh + (size_t)row * 128 + kc * 32 + fk * 8;
            ah[ri] = ok ? *(const short8*)ph : z8;
            if (!second) {
                const unsigned short* pl = Xl + (size_t)row * 128 + kc * 32 + fk * 8;
                al[ri] = ok ? *(const short8*)pl : z8;
            }
        }
#pragma unroll
        for (int ci = 0; ci < 4; ++ci) {
            int col = wc + ci * 16 + frow;
            int g = kc * 4 + fk;
            int go = (g ^ (col & 7)) * 8;
            bh[ci] = *(const short8*)(lds + col * 128 + go);
            bl[ci] = *(const short8*)(lds + 16384 + col * 128 + go);
        }
        if (!second) {
#pragma unroll
            for (int ri = 0; ri < 4; ++ri)
#pragma unroll
                for (int ci = 0; ci < 4; ++ci) {
                    acc[ri][ci] = MFMA16(ah[ri], bh[ci], acc[ri][ci], 0, 0, 0);
                    acc[ri][ci] = MFMA16(ah[ri], bl[ci], acc[ri][ci], 0, 0, 0);
                    acc[ri][ci] = MFMA16(al[ri], bh[ci], acc[ri][ci], 0, 0, 0);
                }
        } else {
#pragma unroll
            for (int ri = 0; ri < 4; ++ri)
#pragma unroll
                for (int ci = 0; ci < 4; ++ci) {
                    acc[ri][ci] = MFMA16(ah[ri], bh[ci], acc[ri][ci], 0, 0, 0);
                    acc[ri][ci] = MFMA16(ah[ri], bl[ci], acc[ri][ci], 0, 0, 0);
                }
        }
    }

    const float* dA = second ? dA1 : dA0;
    const float* dB = second ? nullptr : dB0;
    unsigned short* So = lds;
    float* dotbuf = (float*)(lds + 16384);

    float dotA[4][4] = {}, dotB[4][4] = {};
    __syncthreads();
#pragma unroll
    for (int ci = 0; ci < 4; ++ci) {
        int col = wc + ci * 16 + frow;
        float bcol = bias[col];
        float dAc = dA ? dA[col] : 0.f;
        float dBc = dB ? dB[col] : 0.f;
#pragma unroll
        for (int ri = 0; ri < 4; ++ri) {
            f32x4 v = acc[ri][ci];
#pragma unroll
            for (int reg = 0; reg < 4; ++reg) {
                float val = v[reg] + bcol;
                int row = wr + ri * 16 + q4 * 4 + reg;
                int dw = (col >> 1) ^ ((row & 12) << 1);
                So[row * 128 + dw * 2 + (col & 1)] = (unsigned short)f2bf(val);
                dotA[ri][reg] = fmaf(val, dAc, dotA[ri][reg]);
                dotB[ri][reg] = fmaf(val, dBc, dotB[ri][reg]);
            }
        }
    }
#pragma unroll
    for (int m = 1; m < 16; m <<= 1)
#pragma unroll
        for (int ri = 0; ri < 4; ++ri)
#pragma unroll
            for (int reg = 0; reg < 4; ++reg) {
                dotA[ri][reg] += __shfl_xor(dotA[ri][reg], m, 64);
                dotB[ri][reg] += __shfl_xor(dotB[ri][reg], m, 64);
            }
    if (frow == 0) {
#pragma unroll
        for (int ri = 0; ri < 4; ++ri)
#pragma unroll
            for (int reg = 0; reg < 4; ++reg) {
                int rl = wr + ri * 16 + q4 * 4 + reg;
                dotbuf[(0 * 128 + rl) * 2 + (w & 1)] = dotA[ri][reg];
                dotbuf[(1 * 128 + rl) * 2 + (w & 1)] = dotB[ri][reg];
            }
    }
    __syncthreads();

#pragma unroll
    for (int q = 0; q < 8; ++q) {
        int idx = q * 256 + tid;
        int row = idx >> 4;
        int gc = idx & 15;
        int dwb = (gc * 4) ^ ((row & 12) << 1);
        uint4 vv = *(const uint4*)(So + row * 128 + dwb * 2);
        int grow = r0 + row;
        if (grow < N) *(uint4*)(Yb + (size_t)grow * 128 + gc * 8) = vv;
    }
    {
        int d = tid >> 7, rl = tid & 127;
        int grow = r0 + rl;
        float* oA = second ? oA1 : oA0;
        float* oB = second ? nullptr : oB0;
        if (grow < N) {
            float v = dotbuf[(d * 128 + rl) * 2] + dotbuf[(d * 128 + rl) * 2 + 1];
            if (d == 0) { if (oA) oA[grow] = v; }
            else        { if (oB) oB[grow] = v; }
        }
    }
}

// ---------------- aggregation ----------------
__global__ __launch_bounds__(256) void k_agg(
    const unsigned short* __restrict__ xnb, const unsigned short* __restrict__ hbf,
    const float* __restrict__ x1a, const float* __restrict__ xa2a,
    const float* __restrict__ h1a, const int* __restrict__ rp,
    const int* __restrict__ ts,
    unsigned short* __restrict__ hhi, int N) {
    __shared__ uint2 ew[4][64];
    const int wid = threadIdx.x >> 6;
    const int lane = threadIdx.x & 63;
    const int u = blockIdx.x * 4 + wid;
    if (u >= N) return;
    const int l2 = lane << 1;
    float x1u = x1a[u];
    float w2 = expf(lrelu02(x1u + xa2a[u]));
    float2 xr = bf2f2(*(const unsigned int*)(xnb + (size_t)u * 128 + l2));
    float accx = w2 * xr.x, accy = w2 * xr.y;
    float div = w2;
    int p0 = rp[u], p1 = rp[u + 1];
    for (int base = p0; base < p1; base += 64) {
        int e = base + lane;
        uint2 pk = make_uint2(0u, 0u);
        if (e < p1) {
            int tv = ts[e];
            pk.x = (unsigned int)tv;
            pk.y = __float_as_uint(expf(lrelu02(x1u + h1a[tv])));
        }
        ew[wid][lane] = pk;
        int m = p1 - base; if (m > 64) m = 64;
        int m8 = (m + 7) & ~7;
        for (int j = 0; j < m8; j += 8) {
            uint2 q[8];
#pragma unroll
            for (int k = 0; k < 8; ++k) q[k] = ew[wid][j + k];
            unsigned int hv[8];
#pragma unroll
            for (int k = 0; k < 8; ++k)
                hv[k] = *(const unsigned int*)(hbf + (size_t)q[k].x * 128 + l2);
#pragma unroll
            for (int k = 0; k < 8; ++k) {
                float ww = __uint_as_float(q[k].y);
                float2 f = bf2f2(hv[k]);
                accx = fmaf(ww, f.x, accx);
                accy = fmaf(ww, f.y, accy);
                div += ww;
            }
        }
    }
    float ox = accx / div, oy = accy / div;
    ox = ox > 0.f ? ox : expf(ox) - 1.f;
    oy = oy > 0.f ? oy : expf(oy) - 1.f;
    unsigned int hx = __float_as_uint(ox), hy = __float_as_uint(oy);
    *(unsigned int*)(hhi + (size_t)u * 128 + l2) = (hx >> 16) | (hy & 0xffff0000u);
}

// ---------------- launch ----------------
extern "C" void kernel_launch(void* const* d_in, const int* in_sizes, int n_in,
                              void* d_out, int out_size, void* d_ws, size_t ws_size,
                              hipStream_t stream) {
    const float* x_in = (const float*)d_in[0];
    const int*   s    = (const int*)d_in[1];
    const int*   t    = (const int*)d_in[2];
    const float* fc1W = (const float*)d_in[3];
    const float* fc1b = (const float*)d_in[4];
    const float* fcsW = (const float*)d_in[5];
    const float* fcsb = (const float*)d_in[6];
    const float* a1   = (const float*)d_in[7];
    const float* a2   = (const float*)d_in[8];
    const float* fc2W = (const float*)d_in[9];
    const float* fc2b = (const float*)d_in[10];

    const int N = in_sizes[0] / 256;  // 50000
    const int E = in_sizes[1];        // 800000
    const int G = (N + 255) / 256;
    const int NB = (N + 127) / 128;   // 391

    char* ws = (char*)d_ws;
    size_t off = 0;
    auto alloc = [&](size_t bytes) -> void* {
        void* p = ws + off;
        off += (bytes + 255) & ~(size_t)255;
        return p;
    };
    unsigned short* xbuf_hi = (unsigned short*)alloc((size_t)N * 128 * 2);
    unsigned short* xbuf_lo = (unsigned short*)alloc((size_t)N * 128 * 2);
    unsigned short* h_hi    = (unsigned short*)alloc((size_t)N * 128 * 2);
    unsigned short* xnb     = (unsigned short*)alloc((size_t)N * 128 * 2);
    unsigned short* hbf     = (unsigned short*)alloc((size_t)N * 128 * 2);
    unsigned short* Whi  = (unsigned short*)alloc((size_t)10 * 128 * 128 * 2);
    unsigned short* Wlo  = (unsigned short*)alloc((size_t)10 * 128 * 128 * 2);
    unsigned short* W1hi = (unsigned short*)alloc((size_t)128 * 256 * 2);
    unsigned short* W1lo = (unsigned short*)alloc((size_t)128 * 256 * 2);
    unsigned short* W2hi = (unsigned short*)alloc((size_t)64 * 128 * 2);
    unsigned short* W2lo = (unsigned short*)alloc((size_t)64 * 128 * 2);
    float* x1a  = (float*)alloc((size_t)N * 4);
    float* xa2a = (float*)alloc((size_t)N * 4);
    float* h1a  = (float*)alloc((size_t)N * 4);
    int* row_ptr  = (int*)alloc((size_t)(N + 1) * 4);
    int* cnt      = (int*)alloc((size_t)N * 4);
    int* bsums    = (int*)alloc((size_t)256 * 4);
    int* t_sorted = (int*)alloc((size_t)E * 4);

    // CSR build
    hipMemsetAsync(cnt, 0, (size_t)N * 4, stream);
    k_count<<<(E + 255) / 256, 256, 0, stream>>>(s, cnt, E);
    k_scan1<<<G, 256, 0, stream>>>(cnt, bsums, N);
    k_scan2<<<1, 256, 0, stream>>>(bsums, G);
    k_scan3<<<G, 256, 0, stream>>>(cnt, bsums, row_ptr, N);
    hipMemsetAsync(cnt, 0, (size_t)N * 4, stream);
    k_scatter<<<(E + 255) / 256, 256, 0, stream>>>(s, t, row_ptr, cnt, t_sorted, E);

    // W splits (hops + fc1 + fc2)
    k_wsplit<<<(10 * 128 * 128 + 255) / 256, 256, 0, stream>>>(fcsW, Whi, Wlo, 10 * 128 * 128);
    k_wsplit<<<(128 * 256 + 255) / 256, 256, 0, stream>>>(fc1W, W1hi, W1lo, 128 * 256);
    k_wsplit<<<(64 * 128 + 255) / 256, 256, 0, stream>>>(fc2W, W2hi, W2lo, 64 * 128);

    // fc1 + relu -> split planes (barrier-free)
    k_fc1<<<NB, 256, 0, stream>>>(x_in, W1hi, W1lo, fc1b, xbuf_hi, xbuf_lo, N);

    // hops
    for (int i = 0; i < 10; ++i) {
        const unsigned short* Wh = Whi + (size_t)i * 128 * 128;
        const unsigned short* Wl = Wlo + (size_t)i * 128 * 128;
        const float* b   = fcsb + (size_t)i * 128;
        const float* a1i = a1 + (size_t)i * 128;
        const float* a2i = a2 + (size_t)i * 128;
        if (i == 0) {
            k_mm_bf<<<NB, 256, 0, stream>>>(xbuf_hi, xbuf_lo, NB, h_hi,
                                            Wh, Wl, b, xnb, hbf, N,
                                            a1i, x1a, a2i, xa2a, a2i, h1a);
            k_agg<<<(N + 3) / 4, 256, 0, stream>>>(xnb, xnb, x1a, xa2a, xa2a,
                                                   row_ptr, t_sorted, h_hi, N);
        } else {
            k_mm_bf<<<2 * NB, 256, 0, stream>>>(xbuf_hi, xbuf_lo, NB, h_hi,
                                                Wh, Wl, b, xnb, hbf, N,
                                                a1i, x1a, a2i, xa2a, a2i, h1a);
            k_agg<<<(N + 3) / 4, 256, 0, stream>>>(xnb, hbf, x1a, xa2a, h1a,
                                                   row_ptr, t_sorted, h_hi, N);
        }
    }

    // fc2 (barrier-free, 2-term)
    k_fc2<<<(N + 63) / 64, 256, 0, stream>>>(h_hi, W2hi, W2lo, fc2b, (float*)d_out, N);
}

// Round 10
// 851.559 us; speedup vs baseline: 1.3813x; 1.0093x over previous
//
#include <hip/hip_runtime.h>
#include <math.h>

// ---------------------------------------------------------------------------
// GTAN2 R10: occupancy + critical-path round.
//  - fc1 BM=64 (782 blocks, was 391 at 1.5 blk/CU).
//  - k_xall: ALL 10 hop X-GEMMs (x@Wi^T, loop-invariant x) in ONE dispatch
//    (3910 blocks), outputs xnb/x1a/xa2a per hop; removes X path from the
//    per-hop critical chain. ws_size-guarded (falls back to per-hop).
//  - k_hh: per-hop H GEMM, BM=64, zero W-LDS (W from L2), 16KB C-stage LDS.
//  - hop 0: no k_hh (h==x). k_agg/fc2/CSR unchanged.
// ---------------------------------------------------------------------------

typedef __attribute__((ext_vector_type(8))) short short8;
typedef __attribute__((ext_vector_type(4))) float f32x4;
#define MFMA16 __builtin_amdgcn_mfma_f32_16x16x32_bf16

__device__ __forceinline__ float lrelu02(float v) { return v > 0.f ? v : 0.2f * v; }

__device__ __forceinline__ float2 bf2f2(unsigned int v) {
    return make_float2(__uint_as_float(v << 16), __uint_as_float(v & 0xffff0000u));
}
__device__ __forceinline__ unsigned int f2bf(float f) {  // RNE bf16
    unsigned int u = __float_as_uint(f);
    u += 0x7fffu + ((u >> 16) & 1u);
    return u >> 16;
}
__device__ __forceinline__ float hi_part(float f) {
    return __uint_as_float(__float_as_uint(f) & 0xffff0000u);
}
__device__ __forceinline__ uint4 pack_hi(const float4& a, const float4& b) {
    uint4 r;
    r.x = (__float_as_uint(a.x) >> 16) | (__float_as_uint(a.y) & 0xffff0000u);
    r.y = (__float_as_uint(a.z) >> 16) | (__float_as_uint(a.w) & 0xffff0000u);
    r.z = (__float_as_uint(b.x) >> 16) | (__float_as_uint(b.y) & 0xffff0000u);
    r.w = (__float_as_uint(b.z) >> 16) | (__float_as_uint(b.w) & 0xffff0000u);
    return r;
}
__device__ __forceinline__ uint4 pack_lo(const float4& a, const float4& b) {
    uint4 r;
    r.x = f2bf(a.x - hi_part(a.x)) | (f2bf(a.y - hi_part(a.y)) << 16);
    r.y = f2bf(a.z - hi_part(a.z)) | (f2bf(a.w - hi_part(a.w)) << 16);
    r.z = f2bf(b.x - hi_part(b.x)) | (f2bf(b.y - hi_part(b.y)) << 16);
    r.w = f2bf(b.z - hi_part(b.z)) | (f2bf(b.w - hi_part(b.w)) << 16);
    return r;
}

// ---------------- CSR build ----------------
__global__ __launch_bounds__(256) void k_count(const int* __restrict__ s, int* __restrict__ cnt, int E) {
    int e = blockIdx.x * 256 + threadIdx.x;
    if (e < E) atomicAdd(&cnt[s[e]], 1);
}

__global__ __launch_bounds__(256) void k_scan1(const int* __restrict__ cnt, int* __restrict__ bs, int N) {
    __shared__ int sh[256];
    int idx = blockIdx.x * 256 + threadIdx.x;
    sh[threadIdx.x] = (idx < N) ? cnt[idx] : 0;
    __syncthreads();
#pragma unroll
    for (int off = 128; off; off >>= 1) {
        if (threadIdx.x < off) sh[threadIdx.x] += sh[threadIdx.x + off];
        __syncthreads();
    }
    if (threadIdx.x == 0) bs[blockIdx.x] = sh[0];
}

__global__ __launch_bounds__(256) void k_scan2(int* __restrict__ bs, int G) {
    __shared__ int sh[256];
    int t = threadIdx.x;
    int v = (t < G) ? bs[t] : 0;
    sh[t] = v;
    __syncthreads();
    int val = v;
#pragma unroll
    for (int off = 1; off < 256; off <<= 1) {
        int o = (t >= off) ? sh[t - off] : 0;
        __syncthreads();
        val += o; sh[t] = val;
        __syncthreads();
    }
    if (t < G) bs[t] = val - v;  // exclusive
}

__global__ __launch_bounds__(256) void k_scan3(const int* __restrict__ cnt, const int* __restrict__ bs,
                                               int* __restrict__ rp, int N) {
    __shared__ int sh[256];
    int t = threadIdx.x;
    int idx = blockIdx.x * 256 + t;
    int v = (idx < N) ? cnt[idx] : 0;
    sh[t] = v;
    __syncthreads();
    int val = v;
#pragma unroll
    for (int off = 1; off < 256; off <<= 1) {
        int o = (t >= off) ? sh[t - off] : 0;
        __syncthreads();
        val += o; sh[t] = val;
        __syncthreads();
    }
    if (idx <= N) rp[idx] = val - v + bs[blockIdx.x];
}

__global__ __launch_bounds__(256) void k_scatter(const int* __restrict__ s, const int* __restrict__ t,
                                                 const int* __restrict__ rp, int* __restrict__ cursor,
                                                 int* __restrict__ t_sorted, int E) {
    int e = blockIdx.x * 256 + threadIdx.x;
    if (e < E) {
        int u = s[e];
        int pos = atomicAdd(&cursor[u], 1);
        t_sorted[rp[u] + pos] = t[e];
    }
}

// ---------------- W split ----------------
__global__ __launch_bounds__(256) void k_wsplit(const float* __restrict__ W,
                                                unsigned short* __restrict__ Whi,
                                                unsigned short* __restrict__ Wlo, int total) {
    int i = blockIdx.x * 256 + threadIdx.x;
    if (i < total) {
        float f = W[i];
        unsigned int u = __float_as_uint(f);
        Whi[i] = (unsigned short)(u >> 16);
        Wlo[i] = (unsigned short)f2bf(f - __uint_as_float(u & 0xffff0000u));
    }
}

// ---------------- fc1: barrier-free, zero-LDS, 3-term, BM=64 ----------------
__global__ __launch_bounds__(256) void k_fc1(
    const float* __restrict__ Xf,
    const unsigned short* __restrict__ Wh, const unsigned short* __restrict__ Wl,
    const float* __restrict__ bias,
    unsigned short* __restrict__ Yhi, unsigned short* __restrict__ Ylo, int N) {
    const int tid = threadIdx.x;
    const int r0 = blockIdx.x * 64;
    const int lane = tid & 63;
    const int w = tid >> 6;
    const int wr = (w >> 1) * 32, wc = (w & 1) * 64;
    const int frow = lane & 15;
    const int fk = lane >> 4;
    const int q4 = lane >> 4;

    f32x4 acc[2][4];
#pragma unroll
    for (int i = 0; i < 2; ++i)
#pragma unroll
        for (int j = 0; j < 4; ++j) acc[i][j] = (f32x4){0.f, 0.f, 0.f, 0.f};

    const float4 z4 = make_float4(0.f, 0.f, 0.f, 0.f);
#pragma unroll
    for (int kc = 0; kc < 8; ++kc) {
        short8 ah[2], al[2];
#pragma unroll
        for (int ri = 0; ri < 2; ++ri) {
            int row = r0 + wr + ri * 16 + frow;
            float4 va = z4, vb = z4;
            if (row < N) {
                const float* p = Xf + (size_t)row * 256 + kc * 32 + fk * 8;
                va = *(const float4*)p;
                vb = *(const float4*)(p + 4);
            }
            uint4 h = pack_hi(va, vb);
            uint4 l = pack_lo(va, vb);
            ah[ri] = *(short8*)&h;
            al[ri] = *(short8*)&l;
        }
#pragma unroll
        for (int ci = 0; ci < 4; ++ci) {
            int col = wc + ci * 16 + frow;
            short8 bh = *(const short8*)(Wh + (size_t)col * 256 + kc * 32 + fk * 8);
            short8 bl = *(const short8*)(Wl + (size_t)col * 256 + kc * 32 + fk * 8);
#pragma unroll
            for (int ri = 0; ri < 2; ++ri) {
                acc[ri][ci] = MFMA16(ah[ri], bh, acc[ri][ci], 0, 0, 0);
                acc[ri][ci] = MFMA16(ah[ri], bl, acc[ri][ci], 0, 0, 0);
                acc[ri][ci] = MFMA16(al[ri], bh, acc[ri][ci], 0, 0, 0);
            }
        }
    }

#pragma unroll
    for (int ci = 0; ci < 4; ++ci) {
        int col = wc + ci * 16 + frow;
        float bcol = bias[col];
#pragma unroll
        for (int ri = 0; ri < 2; ++ri) {
            f32x4 v = acc[ri][ci];
#pragma unroll
            for (int reg = 0; reg < 4; ++reg) {
                int grow = r0 + wr + ri * 16 + q4 * 4 + reg;
                if (grow < N) {
                    float val = fmaxf(v[reg] + bcol, 0.f);
                    Yhi[(size_t)grow * 128 + col] = (unsigned short)(__float_as_uint(val) >> 16);
                    Ylo[(size_t)grow * 128 + col] = (unsigned short)f2bf(val - hi_part(val));
                }
            }
        }
    }
}

// ---------------- fc2: barrier-free, zero-LDS, 2-term, BM=64 ----------------
__global__ __launch_bounds__(256) void k_fc2(
    const unsigned short* __restrict__ Xhi,
    const unsigned short* __restrict__ Wh, const unsigned short* __restrict__ Wl,
    const float* __restrict__ bias, float* __restrict__ Yf, int N) {
    const int tid = threadIdx.x;
    const int r0 = blockIdx.x * 64;
    const int lane = tid & 63;
    const int w = tid >> 6;
    const int wr = w * 16;
    const int frow = lane & 15;
    const int fk = lane >> 4;
    const int q4 = lane >> 4;

    f32x4 acc[4];
#pragma unroll
    for (int j = 0; j < 4; ++j) acc[j] = (f32x4){0.f, 0.f, 0.f, 0.f};

    const short8 z8 = (short8){0, 0, 0, 0, 0, 0, 0, 0};
#pragma unroll
    for (int kc = 0; kc < 4; ++kc) {
        int row = r0 + wr + frow;
        short8 ah = (row < N) ? *(const short8*)(Xhi + (size_t)row * 128 + kc * 32 + fk * 8) : z8;
#pragma unroll
        for (int ci = 0; ci < 4; ++ci) {
            int col = ci * 16 + frow;
            short8 bh = *(const short8*)(Wh + (size_t)col * 128 + kc * 32 + fk * 8);
            short8 bl = *(const short8*)(Wl + (size_t)col * 128 + kc * 32 + fk * 8);
            acc[ci] = MFMA16(ah, bh, acc[ci], 0, 0, 0);
            acc[ci] = MFMA16(ah, bl, acc[ci], 0, 0, 0);
        }
    }

#pragma unroll
    for (int ci = 0; ci < 4; ++ci) {
        int col = ci * 16 + frow;
        float bcol = bias[col];
#pragma unroll
        for (int reg = 0; reg < 4; ++reg) {
            int grow = r0 + wr + q4 * 4 + reg;
            if (grow < N) Yf[(size_t)grow * 64 + col] = acc[ci][reg] + bcol;
        }
    }
}

// ---------------- k_xall: batched X GEMMs (x @ Wi^T), W-in-LDS, 3-term ------
// Block b: hop slot = b/NB, row tile = b%NB. Outputs per slot: xnb bf16,
// x1a (dot a1), xa2a (dot a2).
__global__ __launch_bounds__(256) void k_xall(
    const unsigned short* __restrict__ Xhi, const unsigned short* __restrict__ Xlo, int NB,
    const unsigned short* __restrict__ Whi_all, const unsigned short* __restrict__ Wlo_all,
    const float* __restrict__ fcsb, const float* __restrict__ a1, const float* __restrict__ a2,
    int i0, unsigned short* __restrict__ xnb_all,
    float* __restrict__ x1a_all, float* __restrict__ xa2a_all, int N) {
    __shared__ unsigned short lds[2 * 128 * 128];  // 64 KB

    const int tid = threadIdx.x;
    const int islot = (int)blockIdx.x / NB;
    const int bx = (int)blockIdx.x % NB;
    const int ih = i0 + islot;
    const unsigned short* Wh = Whi_all + (size_t)ih * 16384;
    const unsigned short* Wl = Wlo_all + (size_t)ih * 16384;
    const float* bias = fcsb + ih * 128;
    const float* dA = a1 + ih * 128;
    const float* dB = a2 + ih * 128;
    unsigned short* Yb = xnb_all + (size_t)islot * N * 128;
    float* oA = x1a_all + (size_t)islot * N;
    float* oB = xa2a_all + (size_t)islot * N;
    const int r0 = bx * 128;

    {
        int col = tid & 127;
        int pl = tid >> 7;
        const unsigned short* wp = (pl ? Wl : Wh) + (size_t)col * 128;
        unsigned short* dst = lds + pl * 16384 + col * 128;
#pragma unroll
        for (int g = 0; g < 16; ++g)
            *(uint4*)(dst + ((g ^ (col & 7)) * 8)) = ((const uint4*)wp)[g];
    }
    __syncthreads();

    const int lane = tid & 63;
    const int w = tid >> 6;
    const int wr = (w >> 1) * 64, wc = (w & 1) * 64;
    const int frow = lane & 15;
    const int fk = lane >> 4;
    const int q4 = lane >> 4;

    f32x4 acc[4][4];
#pragma unroll
    for (int i = 0; i < 4; ++i)
#pragma unroll
        for (int j = 0; j < 4; ++j) acc[i][j] = (f32x4){0.f, 0.f, 0.f, 0.f};

    const short8 z8 = (short8){0, 0, 0, 0, 0, 0, 0, 0};

#pragma unroll
    for (int kc = 0; kc < 4; ++kc) {
        short8 ah[4], al[4], bh[4], bl[4];
#pragma unroll
        for (int ri = 0; ri < 4; ++ri) {
            int row = r0 + wr + ri * 16 + frow;
            bool ok = row < N;
            ah[ri] = ok ? *(const short8*)(Xhi + (size_t)row * 128 + kc * 32 + fk * 8) : z8;
            al[ri] = ok ? *(const short8*)(Xlo + (size_t)row * 128 + kc * 32 + fk * 8) : z8;
        }
#pragma unroll
        for (int ci = 0; ci < 4; ++ci) {
            int col = wc + ci * 16 + frow;
            int g = kc * 4 + fk;
            int go = (g ^ (col & 7)) * 8;
            bh[ci] = *(const short8*)(lds + col * 128 + go);
            bl[ci] = *(const short8*)(lds + 16384 + col * 128 + go);
        }
#pragma unroll
        for (int ri = 0; ri < 4; ++ri)
#pragma unroll
            for (int ci = 0; ci < 4; ++ci) {
                acc[ri][ci] = MFMA16(ah[ri], bh[ci], acc[ri][ci], 0, 0, 0);
                acc[ri][ci] = MFMA16(ah[ri], bl[ci], acc[ri][ci], 0, 0, 0);
                acc[ri][ci] = MFMA16(al[ri], bh[ci], acc[ri][ci], 0, 0, 0);
            }
    }

    unsigned short* So = lds;
    float* dotbuf = (float*)(lds + 16384);

    float dotA[4][4] = {}, dotB[4][4] = {};
    __syncthreads();
#pragma unroll
    for (int ci = 0; ci < 4; ++ci) {
        int col = wc + ci * 16 + frow;
        float bcol = bias[col];
        float dAc = dA[col];
        float dBc = dB[col];
#pragma unroll
        for (int ri = 0; ri < 4; ++ri) {
            f32x4 v = acc[ri][ci];
#pragma unroll
            for (int reg = 0; reg < 4; ++reg) {
                float val = v[reg] + bcol;
                int row = wr + ri * 16 + q4 * 4 + reg;
                int dw = (col >> 1) ^ ((row & 12) << 1);
                So[row * 128 + dw * 2 + (col & 1)] = (unsigned short)f2bf(val);
                dotA[ri][reg] = fmaf(val, dAc, dotA[ri][reg]);
                dotB[ri][reg] = fmaf(val, dBc, dotB[ri][reg]);
            }
        }
    }
#pragma unroll
    for (int m = 1; m < 16; m <<= 1)
#pragma unroll
        for (int ri = 0; ri < 4; ++ri)
#pragma unroll
            for (int reg = 0; reg < 4; ++reg) {
                dotA[ri][reg] += __shfl_xor(dotA[ri][reg], m, 64);
                dotB[ri][reg] += __shfl_xor(dotB[ri][reg], m, 64);
            }
    if (frow == 0) {
#pragma unroll
        for (int ri = 0; ri < 4; ++ri)
#pragma unroll
            for (int reg = 0; reg < 4; ++reg) {
                int rl = wr + ri * 16 + q4 * 4 + reg;
                dotbuf[(0 * 128 + rl) * 2 + (w & 1)] = dotA[ri][reg];
                dotbuf[(1 * 128 + rl) * 2 + (w & 1)] = dotB[ri][reg];
            }
    }
    __syncthreads();

#pragma unroll
    for (int q = 0; q < 8; ++q) {
        int idx = q * 256 + tid;
        int row = idx >> 4;
        int gc = idx & 15;
        int dwb = (gc * 4) ^ ((row & 12) << 1);
        uint4 vv = *(const uint4*)(So + row * 128 + dwb * 2);
        int grow = r0 + row;
        if (grow < N) *(uint4*)(Yb + (size_t)grow * 128 + gc * 8) = vv;
    }
    {
        int d = tid >> 7, rl = tid & 127;
        int grow = r0 + rl;
        if (grow < N) {
            float v = dotbuf[(d * 128 + rl) * 2] + dotbuf[(d * 128 + rl) * 2 + 1];
            if (d == 0) oA[grow] = v;
            else        oB[grow] = v;
        }
    }
}

// ---------------- k_hh: per-hop H GEMM, BM=64, zero W-LDS, 2-term -----------
__global__ __launch_bounds__(256) void k_hh(
    const unsigned short* __restrict__ Hhi,
    const unsigned short* __restrict__ Wh, const unsigned short* __restrict__ Wl,
    const float* __restrict__ bias, const float* __restrict__ dA2,
    unsigned short* __restrict__ hbf, float* __restrict__ h1a, int N) {
    __shared__ unsigned short So[64 * 128];  // 16 KB C-stage
    __shared__ float dotbuf[64][2];
    const int tid = threadIdx.x;
    const int r0 = blockIdx.x * 64;
    const int lane = tid & 63;
    const int w = tid >> 6;
    const int wr = (w >> 1) * 32, wc = (w & 1) * 64;
    const int frow = lane & 15;
    const int fk = lane >> 4;
    const int q4 = lane >> 4;

    f32x4 acc[2][4];
#pragma unroll
    for (int i = 0; i < 2; ++i)
#pragma unroll
        for (int j = 0; j < 4; ++j) acc[i][j] = (f32x4){0.f, 0.f, 0.f, 0.f};

    const short8 z8 = (short8){0, 0, 0, 0, 0, 0, 0, 0};
#pragma unroll
    for (int kc = 0; kc < 4; ++kc) {
        short8 ah[2];
#pragma unroll
        for (int ri = 0; ri < 2; ++ri) {
            int row = r0 + wr + ri * 16 + frow;
            ah[ri] = (row < N) ? *(const short8*)(Hhi + (size_t)row * 128 + kc * 32 + fk * 8) : z8;
        }
#pragma unroll
        for (int ci = 0; ci < 4; ++ci) {
            int col = wc + ci * 16 + frow;
            short8 bh = *(const short8*)(Wh + (size_t)col * 128 + kc * 32 + fk * 8);
            short8 bl = *(const short8*)(Wl + (size_t)col * 128 + kc * 32 + fk * 8);
#pragma unroll
            for (int ri = 0; ri < 2; ++ri) {
                acc[ri][ci] = MFMA16(ah[ri], bh, acc[ri][ci], 0, 0, 0);
                acc[ri][ci] = MFMA16(ah[ri], bl, acc[ri][ci], 0, 0, 0);
            }
        }
    }

    float dotA[2][4] = {};
#pragma unroll
    for (int ci = 0; ci < 4; ++ci) {
        int col = wc + ci * 16 + frow;
        float bcol = bias[col];
        float dAc = dA2[col];
#pragma unroll
        for (int ri = 0; ri < 2; ++ri) {
            f32x4 v = acc[ri][ci];
#pragma unroll
            for (int reg = 0; reg < 4; ++reg) {
                float val = v[reg] + bcol;
                int row = wr + ri * 16 + q4 * 4 + reg;
                int dw = (col >> 1) ^ ((row & 12) << 1);
                So[row * 128 + dw * 2 + (col & 1)] = (unsigned short)f2bf(val);
                dotA[ri][reg] = fmaf(val, dAc, dotA[ri][reg]);
            }
        }
    }
#pragma unroll
    for (int m = 1; m < 16; m <<= 1)
#pragma unroll
        for (int ri = 0; ri < 2; ++ri)
#pragma unroll
            for (int reg = 0; reg < 4; ++reg)
                dotA[ri][reg] += __shfl_xor(dotA[ri][reg], m, 64);
    if (frow == 0) {
#pragma unroll
        for (int ri = 0; ri < 2; ++ri)
#pragma unroll
            for (int reg = 0; reg < 4; ++reg) {
                int rl = wr + ri * 16 + q4 * 4 + reg;
                dotbuf[rl][w & 1] = dotA[ri][reg];
            }
    }
    __syncthreads();

#pragma unroll
    for (int q = 0; q < 4; ++q) {
        int idx = q * 256 + tid;        // 0..1023
        int row = idx >> 4;             // 0..63
        int gc = idx & 15;
        int dwb = (gc * 4) ^ ((row & 12) << 1);
        uint4 vv = *(const uint4*)(So + row * 128 + dwb * 2);
        int grow = r0 + row;
        if (grow < N) *(uint4*)(hbf + (size_t)grow * 128 + gc * 8) = vv;
    }
    if (tid < 64) {
        int grow = r0 + tid;
        if (grow < N) h1a[grow] = dotbuf[tid][0] + dotbuf[tid][1];
    }
}

// ---------------- aggregation ----------------
__global__ __launch_bounds__(256) void k_agg(
    const unsigned short* __restrict__ xnb, const unsigned short* __restrict__ hbf,
    const float* __restrict__ x1a, const float* __restrict__ xa2a,
    const float* __restrict__ h1a, const int* __restrict__ rp,
    const int* __restrict__ ts,
    unsigned short* __restrict__ hhi, int N) {
    __shared__ uint2 ew[4][64];
    const int wid = threadIdx.x >> 6;
    const int lane = threadIdx.x & 63;
    const int u = blockIdx.x * 4 + wid;
    if (u >= N) return;
    const int l2 = lane << 1;
    float x1u = x1a[u];
    float w2 = expf(lrelu02(x1u + xa2a[u]));
    float2 xr = bf2f2(*(const unsigned int*)(xnb + (size_t)u * 128 + l2));
    float accx = w2 * xr.x, accy = w2 * xr.y;
    float div = w2;
    int p0 = rp[u], p1 = rp[u + 1];
    for (int base = p0; base < p1; base += 64) {
        int e = base + lane;
        uint2 pk = make_uint2(0u, 0u);
        if (e < p1) {
            int tv = ts[e];
            pk.x = (unsigned int)tv;
            pk.y = __float_as_uint(expf(lrelu02(x1u + h1a[tv])));
        }
        ew[wid][lane] = pk;
        int m = p1 - base; if (m > 64) m = 64;
        int m8 = (m + 7) & ~7;
        for (int j = 0; j < m8; j += 8) {
            uint2 q[8];
#pragma unroll
            for (int k = 0; k < 8; ++k) q[k] = ew[wid][j + k];
            unsigned int hv[8];
#pragma unroll
            for (int k = 0; k < 8; ++k)
                hv[k] = *(const unsigned int*)(hbf + (size_t)q[k].x * 128 + l2);
#pragma unroll
            for (int k = 0; k < 8; ++k) {
                float ww = __uint_as_float(q[k].y);
                float2 f = bf2f2(hv[k]);
                accx = fmaf(ww, f.x, accx);
                accy = fmaf(ww, f.y, accy);
                div += ww;
            }
        }
    }
    float ox = accx / div, oy = accy / div;
    ox = ox > 0.f ? ox : expf(ox) - 1.f;
    oy = oy > 0.f ? oy : expf(oy) - 1.f;
    unsigned int hx = __float_as_uint(ox), hy = __float_as_uint(oy);
    *(unsigned int*)(hhi + (size_t)u * 128 + l2) = (hx >> 16) | (hy & 0xffff0000u);
}

// ---------------- launch ----------------
extern "C" void kernel_launch(void* const* d_in, const int* in_sizes, int n_in,
                              void* d_out, int out_size, void* d_ws, size_t ws_size,
                              hipStream_t stream) {
    const float* x_in = (const float*)d_in[0];
    const int*   s    = (const int*)d_in[1];
    const int*   t    = (const int*)d_in[2];
    const float* fc1W = (const float*)d_in[3];
    const float* fc1b = (const float*)d_in[4];
    const float* fcsW = (const float*)d_in[5];
    const float* fcsb = (const float*)d_in[6];
    const float* a1   = (const float*)d_in[7];
    const float* a2   = (const float*)d_in[8];
    const float* fc2W = (const float*)d_in[9];
    const float* fc2b = (const float*)d_in[10];

    const int N = in_sizes[0] / 256;  // 50000
    const int E = in_sizes[1];        // 800000
    const int G = (N + 255) / 256;
    const int NB = (N + 127) / 128;   // 391
    const int NB64 = (N + 63) / 64;   // 782

    auto A256 = [](size_t b) { return (b + 255) & ~(size_t)255; };
    const size_t plane = A256((size_t)N * 128 * 2);
    const size_t vecN  = A256((size_t)N * 4);
    size_t fixed = 3 * plane                 // xbuf_hi, xbuf_lo, h_hi
                 + plane                     // hbf
                 + 2 * A256((size_t)10 * 16384 * 2)
                 + 2 * A256((size_t)128 * 256 * 2) + 2 * A256((size_t)64 * 128 * 2)
                 + vecN                      // h1a
                 + A256((size_t)(N + 1) * 4) + vecN + A256(1024) + A256((size_t)E * 4);
    const int BATCH = (fixed + 10 * (plane + 2 * vecN) <= ws_size) ? 10 : 1;

    char* ws = (char*)d_ws;
    size_t off = 0;
    auto alloc = [&](size_t bytes) -> void* {
        void* p = ws + off;
        off += (bytes + 255) & ~(size_t)255;
        return p;
    };
    unsigned short* xbuf_hi = (unsigned short*)alloc((size_t)N * 128 * 2);
    unsigned short* xbuf_lo = (unsigned short*)alloc((size_t)N * 128 * 2);
    unsigned short* h_hi    = (unsigned short*)alloc((size_t)N * 128 * 2);
    unsigned short* hbf     = (unsigned short*)alloc((size_t)N * 128 * 2);
    unsigned short* Whi  = (unsigned short*)alloc((size_t)10 * 16384 * 2);
    unsigned short* Wlo  = (unsigned short*)alloc((size_t)10 * 16384 * 2);
    unsigned short* W1hi = (unsigned short*)alloc((size_t)128 * 256 * 2);
    unsigned short* W1lo = (unsigned short*)alloc((size_t)128 * 256 * 2);
    unsigned short* W2hi = (unsigned short*)alloc((size_t)64 * 128 * 2);
    unsigned short* W2lo = (unsigned short*)alloc((size_t)64 * 128 * 2);
    float* h1a  = (float*)alloc((size_t)N * 4);
    int* row_ptr  = (int*)alloc((size_t)(N + 1) * 4);
    int* cnt      = (int*)alloc((size_t)N * 4);
    int* bsums    = (int*)alloc((size_t)1024);
    int* t_sorted = (int*)alloc((size_t)E * 4);
    unsigned short* xnb_all = (unsigned short*)alloc((size_t)BATCH * N * 128 * 2);
    float* x1a_all  = (float*)alloc((size_t)BATCH * N * 4);
    float* xa2a_all = (float*)alloc((size_t)BATCH * N * 4);

    // CSR build
    hipMemsetAsync(cnt, 0, (size_t)N * 4, stream);
    k_count<<<(E + 255) / 256, 256, 0, stream>>>(s, cnt, E);
    k_scan1<<<G, 256, 0, stream>>>(cnt, bsums, N);
    k_scan2<<<1, 256, 0, stream>>>(bsums, G);
    k_scan3<<<G, 256, 0, stream>>>(cnt, bsums, row_ptr, N);
    hipMemsetAsync(cnt, 0, (size_t)N * 4, stream);
    k_scatter<<<(E + 255) / 256, 256, 0, stream>>>(s, t, row_ptr, cnt, t_sorted, E);

    // W splits
    k_wsplit<<<(10 * 16384 + 255) / 256, 256, 0, stream>>>(fcsW, Whi, Wlo, 10 * 16384);
    k_wsplit<<<(128 * 256 + 255) / 256, 256, 0, stream>>>(fc1W, W1hi, W1lo, 128 * 256);
    k_wsplit<<<(64 * 128 + 255) / 256, 256, 0, stream>>>(fc2W, W2hi, W2lo, 64 * 128);

    // fc1 + relu -> split planes
    k_fc1<<<NB64, 256, 0, stream>>>(x_in, W1hi, W1lo, fc1b, xbuf_hi, xbuf_lo, N);

    // batched X GEMMs for all hops (or per-hop fallback)
    if (BATCH == 10)
        k_xall<<<10 * NB, 256, 0, stream>>>(xbuf_hi, xbuf_lo, NB, Whi, Wlo,
                                            fcsb, a1, a2, 0, xnb_all, x1a_all, xa2a_all, N);

    // hops
    for (int i = 0; i < 10; ++i) {
        if (BATCH == 1)
            k_xall<<<NB, 256, 0, stream>>>(xbuf_hi, xbuf_lo, NB, Whi, Wlo,
                                           fcsb, a1, a2, i, xnb_all, x1a_all, xa2a_all, N);
        const int sl = (BATCH == 10) ? i : 0;
        const unsigned short* xnb_i = xnb_all + (size_t)sl * N * 128;
        const float* x1_i  = x1a_all + (size_t)sl * N;
        const float* xa2_i = xa2a_all + (size_t)sl * N;
        if (i == 0) {
            // h == x: hlin == xnew, h1a == xa2a
            k_agg<<<(N + 3) / 4, 256, 0, stream>>>(xnb_i, xnb_i, x1_i, xa2_i, xa2_i,
                                                   row_ptr, t_sorted, h_hi, N);
        } else {
            k_hh<<<NB64, 256, 0, stream>>>(h_hi, Whi + (size_t)i * 16384, Wlo + (size_t)i * 16384,
                                           fcsb + (size_t)i * 128, a2 + (size_t)i * 128,
                                           hbf, h1a, N);
            k_agg<<<(N + 3) / 4, 256, 0, stream>>>(xnb_i, hbf, x1_i, xa2_i, h1a,
                                                   row_ptr, t_sorted, h_hi, N);
        }
    }

    // fc2
    k_fc2<<<NB64, 256, 0, stream>>>(h_hi, W2hi, W2lo, fc2b, (float*)d_out, N);
}

// Round 11
// 806.296 us; speedup vs baseline: 1.4589x; 1.0561x over previous
//
#include <hip/hip_runtime.h>
#include <math.h>

// ---------------------------------------------------------------------------
// GTAN2 R11: aggregate-then-transform. Since hlin = h@W^T+b and x_new =
// x@W^T+b share W (x invariant), h_next = elu(g@W^T + b) with
// g = (sum w1*h[t] + w2*x)/div  — aggregation moves to h-space, so the
// per-hop X-GEMM (k_xall) and hlin materialization are DELETED.
// Scalars via transformed vectors: x1 = x·(W^T a1)+b·a1 (k_prep + k_xdots,
// all hops in one small GEMM), h1 fused into k_gemm epilogue (next hop's v2).
// Per hop: k_agg (gather) -> k_gemm (g->h, elu, h1a dot). fc1/fc2/CSR as R10.
// ---------------------------------------------------------------------------

typedef __attribute__((ext_vector_type(8))) short short8;
typedef __attribute__((ext_vector_type(4))) float f32x4;
#define MFMA16 __builtin_amdgcn_mfma_f32_16x16x32_bf16

__device__ __forceinline__ float lrelu02(float v) { return v > 0.f ? v : 0.2f * v; }

__device__ __forceinline__ float2 bf2f2(unsigned int v) {
    return make_float2(__uint_as_float(v << 16), __uint_as_float(v & 0xffff0000u));
}
__device__ __forceinline__ unsigned int f2bf(float f) {  // RNE bf16
    unsigned int u = __float_as_uint(f);
    u += 0x7fffu + ((u >> 16) & 1u);
    return u >> 16;
}
__device__ __forceinline__ float hi_part(float f) {
    return __uint_as_float(__float_as_uint(f) & 0xffff0000u);
}
__device__ __forceinline__ uint4 pack_hi(const float4& a, const float4& b) {
    uint4 r;
    r.x = (__float_as_uint(a.x) >> 16) | (__float_as_uint(a.y) & 0xffff0000u);
    r.y = (__float_as_uint(a.z) >> 16) | (__float_as_uint(a.w) & 0xffff0000u);
    r.z = (__float_as_uint(b.x) >> 16) | (__float_as_uint(b.y) & 0xffff0000u);
    r.w = (__float_as_uint(b.z) >> 16) | (__float_as_uint(b.w) & 0xffff0000u);
    return r;
}
__device__ __forceinline__ uint4 pack_lo(const float4& a, const float4& b) {
    uint4 r;
    r.x = f2bf(a.x - hi_part(a.x)) | (f2bf(a.y - hi_part(a.y)) << 16);
    r.y = f2bf(a.z - hi_part(a.z)) | (f2bf(a.w - hi_part(a.w)) << 16);
    r.z = f2bf(b.x - hi_part(b.x)) | (f2bf(b.y - hi_part(b.y)) << 16);
    r.w = f2bf(b.z - hi_part(b.z)) | (f2bf(b.w - hi_part(b.w)) << 16);
    return r;
}

// ---------------- CSR build ----------------
__global__ __launch_bounds__(256) void k_count(const int* __restrict__ s, int* __restrict__ cnt, int E) {
    int e = blockIdx.x * 256 + threadIdx.x;
    if (e < E) atomicAdd(&cnt[s[e]], 1);
}

__global__ __launch_bounds__(256) void k_scan1(const int* __restrict__ cnt, int* __restrict__ bs, int N) {
    __shared__ int sh[256];
    int idx = blockIdx.x * 256 + threadIdx.x;
    sh[threadIdx.x] = (idx < N) ? cnt[idx] : 0;
    __syncthreads();
#pragma unroll
    for (int off = 128; off; off >>= 1) {
        if (threadIdx.x < off) sh[threadIdx.x] += sh[threadIdx.x + off];
        __syncthreads();
    }
    if (threadIdx.x == 0) bs[blockIdx.x] = sh[0];
}

__global__ __launch_bounds__(256) void k_scan2(int* __restrict__ bs, int G) {
    __shared__ int sh[256];
    int t = threadIdx.x;
    int v = (t < G) ? bs[t] : 0;
    sh[t] = v;
    __syncthreads();
    int val = v;
#pragma unroll
    for (int off = 1; off < 256; off <<= 1) {
        int o = (t >= off) ? sh[t - off] : 0;
        __syncthreads();
        val += o; sh[t] = val;
        __syncthreads();
    }
    if (t < G) bs[t] = val - v;  // exclusive
}

__global__ __launch_bounds__(256) void k_scan3(const int* __restrict__ cnt, const int* __restrict__ bs,
                                               int* __restrict__ rp, int N) {
    __shared__ int sh[256];
    int t = threadIdx.x;
    int idx = blockIdx.x * 256 + t;
    int v = (idx < N) ? cnt[idx] : 0;
    sh[t] = v;
    __syncthreads();
    int val = v;
#pragma unroll
    for (int off = 1; off < 256; off <<= 1) {
        int o = (t >= off) ? sh[t - off] : 0;
        __syncthreads();
        val += o; sh[t] = val;
        __syncthreads();
    }
    if (idx <= N) rp[idx] = val - v + bs[blockIdx.x];
}

__global__ __launch_bounds__(256) void k_scatter(const int* __restrict__ s, const int* __restrict__ t,
                                                 const int* __restrict__ rp, int* __restrict__ cursor,
                                                 int* __restrict__ t_sorted, int E) {
    int e = blockIdx.x * 256 + threadIdx.x;
    if (e < E) {
        int u = s[e];
        int pos = atomicAdd(&cursor[u], 1);
        t_sorted[rp[u] + pos] = t[e];
    }
}

// ---------------- W split ----------------
__global__ __launch_bounds__(256) void k_wsplit(const float* __restrict__ W,
                                                unsigned short* __restrict__ Whi,
                                                unsigned short* __restrict__ Wlo, int total) {
    int i = blockIdx.x * 256 + threadIdx.x;
    if (i < total) {
        float f = W[i];
        unsigned int u = __float_as_uint(f);
        Whi[i] = (unsigned short)(u >> 16);
        Wlo[i] = (unsigned short)f2bf(f - __uint_as_float(u & 0xffff0000u));
    }
}

// ---------------- k_prep: V vectors (W^T a1, W^T a2) + constants ------------
// Vf/Vh/Vl layout: row i (<10) = v1_i, row 16+i = v2_i; cvec[i]=b·a1, [16+i]=b·a2.
__global__ __launch_bounds__(256) void k_prep(
    const float* __restrict__ fcsW, const float* __restrict__ fcsb,
    const float* __restrict__ a1, const float* __restrict__ a2,
    float* __restrict__ Vf, unsigned short* __restrict__ Vh,
    unsigned short* __restrict__ Vl, float* __restrict__ cvec) {
    int i = blockIdx.x;
    int t = threadIdx.x;
    const float* W = fcsW + (size_t)i * 16384;
    if (t < 128) {
        float s1 = 0.f, s2 = 0.f;
        for (int j = 0; j < 128; ++j) {
            float w = W[j * 128 + t];
            s1 = fmaf(w, a1[i * 128 + j], s1);
            s2 = fmaf(w, a2[i * 128 + j], s2);
        }
        Vf[i * 128 + t] = s1;
        Vf[(16 + i) * 128 + t] = s2;
        Vh[i * 128 + t] = (unsigned short)(__float_as_uint(s1) >> 16);
        Vl[i * 128 + t] = (unsigned short)f2bf(s1 - hi_part(s1));
        Vh[(16 + i) * 128 + t] = (unsigned short)(__float_as_uint(s2) >> 16);
        Vl[(16 + i) * 128 + t] = (unsigned short)f2bf(s2 - hi_part(s2));
    } else if (t == 128) {
        float c1 = 0.f, c2 = 0.f;
        for (int j = 0; j < 128; ++j) {
            c1 = fmaf(fcsb[i * 128 + j], a1[i * 128 + j], c1);
            c2 = fmaf(fcsb[i * 128 + j], a2[i * 128 + j], c2);
        }
        cvec[i] = c1;
        cvec[16 + i] = c2;
    }
}

// ---------------- fc1: barrier-free, zero-LDS, 3-term, BM=64 ----------------
__global__ __launch_bounds__(256) void k_fc1(
    const float* __restrict__ Xf,
    const unsigned short* __restrict__ Wh, const unsigned short* __restrict__ Wl,
    const float* __restrict__ bias,
    unsigned short* __restrict__ Yhi, unsigned short* __restrict__ Ylo, int N) {
    const int tid = threadIdx.x;
    const int r0 = blockIdx.x * 64;
    const int lane = tid & 63;
    const int w = tid >> 6;
    const int wr = (w >> 1) * 32, wc = (w & 1) * 64;
    const int frow = lane & 15;
    const int fk = lane >> 4;
    const int q4 = lane >> 4;

    f32x4 acc[2][4];
#pragma unroll
    for (int i = 0; i < 2; ++i)
#pragma unroll
        for (int j = 0; j < 4; ++j) acc[i][j] = (f32x4){0.f, 0.f, 0.f, 0.f};

    const float4 z4 = make_float4(0.f, 0.f, 0.f, 0.f);
#pragma unroll
    for (int kc = 0; kc < 8; ++kc) {
        short8 ah[2], al[2];
#pragma unroll
        for (int ri = 0; ri < 2; ++ri) {
            int row = r0 + wr + ri * 16 + frow;
            float4 va = z4, vb = z4;
            if (row < N) {
                const float* p = Xf + (size_t)row * 256 + kc * 32 + fk * 8;
                va = *(const float4*)p;
                vb = *(const float4*)(p + 4);
            }
            uint4 h = pack_hi(va, vb);
            uint4 l = pack_lo(va, vb);
            ah[ri] = *(short8*)&h;
            al[ri] = *(short8*)&l;
        }
#pragma unroll
        for (int ci = 0; ci < 4; ++ci) {
            int col = wc + ci * 16 + frow;
            short8 bh = *(const short8*)(Wh + (size_t)col * 256 + kc * 32 + fk * 8);
            short8 bl = *(const short8*)(Wl + (size_t)col * 256 + kc * 32 + fk * 8);
#pragma unroll
            for (int ri = 0; ri < 2; ++ri) {
                acc[ri][ci] = MFMA16(ah[ri], bh, acc[ri][ci], 0, 0, 0);
                acc[ri][ci] = MFMA16(ah[ri], bl, acc[ri][ci], 0, 0, 0);
                acc[ri][ci] = MFMA16(al[ri], bh, acc[ri][ci], 0, 0, 0);
            }
        }
    }

#pragma unroll
    for (int ci = 0; ci < 4; ++ci) {
        int col = wc + ci * 16 + frow;
        float bcol = bias[col];
#pragma unroll
        for (int ri = 0; ri < 2; ++ri) {
            f32x4 v = acc[ri][ci];
#pragma unroll
            for (int reg = 0; reg < 4; ++reg) {
                int grow = r0 + wr + ri * 16 + q4 * 4 + reg;
                if (grow < N) {
                    float val = fmaxf(v[reg] + bcol, 0.f);
                    Yhi[(size_t)grow * 128 + col] = (unsigned short)(__float_as_uint(val) >> 16);
                    Ylo[(size_t)grow * 128 + col] = (unsigned short)f2bf(val - hi_part(val));
                }
            }
        }
    }
}

// ---------------- k_xdots: x1a/xa2a for ALL hops in one N x 32 GEMM ---------
// B = V planes [32][128] (rows 0-9: v1_i, 16-25: v2_i), 3-term for precision.
__global__ __launch_bounds__(256) void k_xdots(
    const unsigned short* __restrict__ Xhi, const unsigned short* __restrict__ Xlo,
    const unsigned short* __restrict__ Vh, const unsigned short* __restrict__ Vl,
    const float* __restrict__ cvec,
    float* __restrict__ x1a_all, float* __restrict__ xa2a_all, int N) {
    const int tid = threadIdx.x;
    const int r0 = blockIdx.x * 64;
    const int lane = tid & 63;
    const int w = tid >> 6;
    const int wr = w * 16;
    const int frow = lane & 15;
    const int fk = lane >> 4;
    const int q4 = lane >> 4;

    f32x4 acc[2];
    acc[0] = (f32x4){0.f, 0.f, 0.f, 0.f};
    acc[1] = (f32x4){0.f, 0.f, 0.f, 0.f};

    const short8 z8 = (short8){0, 0, 0, 0, 0, 0, 0, 0};
#pragma unroll
    for (int kc = 0; kc < 4; ++kc) {
        int row = r0 + wr + frow;
        bool ok = row < N;
        short8 ah = ok ? *(const short8*)(Xhi + (size_t)row * 128 + kc * 32 + fk * 8) : z8;
        short8 al = ok ? *(const short8*)(Xlo + (size_t)row * 128 + kc * 32 + fk * 8) : z8;
#pragma unroll
        for (int ci = 0; ci < 2; ++ci) {
            int col = ci * 16 + frow;
            short8 bh = *(const short8*)(Vh + (size_t)col * 128 + kc * 32 + fk * 8);
            short8 bl = *(const short8*)(Vl + (size_t)col * 128 + kc * 32 + fk * 8);
            acc[ci] = MFMA16(ah, bh, acc[ci], 0, 0, 0);
            acc[ci] = MFMA16(ah, bl, acc[ci], 0, 0, 0);
            acc[ci] = MFMA16(al, bh, acc[ci], 0, 0, 0);
        }
    }

#pragma unroll
    for (int ci = 0; ci < 2; ++ci) {
        int col = ci * 16 + frow;
        float c = cvec[col];
#pragma unroll
        for (int reg = 0; reg < 4; ++reg) {
            int grow = r0 + wr + q4 * 4 + reg;
            if (grow < N) {
                float val = acc[ci][reg] + c;
                if (col < 10) x1a_all[(size_t)col * N + grow] = val;
                else if (col >= 16 && col < 26) xa2a_all[(size_t)(col - 16) * N + grow] = val;
            }
        }
    }
}

// ---------------- k_gemm: h_next = elu(g @ W^T + b), fused h1a dot ----------
// BM=64, zero W-LDS, A = g bf16 (single plane), B = Wh+Wl (2-term).
__global__ __launch_bounds__(256) void k_gemm(
    const unsigned short* __restrict__ G,
    const unsigned short* __restrict__ Wh, const unsigned short* __restrict__ Wl,
    const float* __restrict__ bias, const float* __restrict__ vnext,
    const float* __restrict__ cnextp,
    unsigned short* __restrict__ Hout, float* __restrict__ h1a, int N) {
    __shared__ unsigned short So[64 * 128];  // 16 KB C-stage
    __shared__ float dotbuf[64][2];
    const int tid = threadIdx.x;
    const int r0 = blockIdx.x * 64;
    const int lane = tid & 63;
    const int w = tid >> 6;
    const int wr = (w >> 1) * 32, wc = (w & 1) * 64;
    const int frow = lane & 15;
    const int fk = lane >> 4;
    const int q4 = lane >> 4;
    const bool dodot = vnext != nullptr;

    f32x4 acc[2][4];
#pragma unroll
    for (int i = 0; i < 2; ++i)
#pragma unroll
        for (int j = 0; j < 4; ++j) acc[i][j] = (f32x4){0.f, 0.f, 0.f, 0.f};

    const short8 z8 = (short8){0, 0, 0, 0, 0, 0, 0, 0};
#pragma unroll
    for (int kc = 0; kc < 4; ++kc) {
        short8 ah[2];
#pragma unroll
        for (int ri = 0; ri < 2; ++ri) {
            int row = r0 + wr + ri * 16 + frow;
            ah[ri] = (row < N) ? *(const short8*)(G + (size_t)row * 128 + kc * 32 + fk * 8) : z8;
        }
#pragma unroll
        for (int ci = 0; ci < 4; ++ci) {
            int col = wc + ci * 16 + frow;
            short8 bh = *(const short8*)(Wh + (size_t)col * 128 + kc * 32 + fk * 8);
            short8 bl = *(const short8*)(Wl + (size_t)col * 128 + kc * 32 + fk * 8);
#pragma unroll
            for (int ri = 0; ri < 2; ++ri) {
                acc[ri][ci] = MFMA16(ah[ri], bh, acc[ri][ci], 0, 0, 0);
                acc[ri][ci] = MFMA16(ah[ri], bl, acc[ri][ci], 0, 0, 0);
            }
        }
    }

    float dotA[2][4] = {};
#pragma unroll
    for (int ci = 0; ci < 4; ++ci) {
        int col = wc + ci * 16 + frow;
        float bcol = bias[col];
        float vc = dodot ? vnext[col] : 0.f;
#pragma unroll
        for (int ri = 0; ri < 2; ++ri) {
            f32x4 v = acc[ri][ci];
#pragma unroll
            for (int reg = 0; reg < 4; ++reg) {
                float val = v[reg] + bcol;
                val = val > 0.f ? val : expf(val) - 1.f;  // elu
                int row = wr + ri * 16 + q4 * 4 + reg;
                int dw = (col >> 1) ^ ((row & 12) << 1);
                So[row * 128 + dw * 2 + (col & 1)] = (unsigned short)f2bf(val);
                dotA[ri][reg] = fmaf(val, vc, dotA[ri][reg]);
            }
        }
    }
#pragma unroll
    for (int m = 1; m < 16; m <<= 1)
#pragma unroll
        for (int ri = 0; ri < 2; ++ri)
#pragma unroll
            for (int reg = 0; reg < 4; ++reg)
                dotA[ri][reg] += __shfl_xor(dotA[ri][reg], m, 64);
    if (frow == 0) {
#pragma unroll
        for (int ri = 0; ri < 2; ++ri)
#pragma unroll
            for (int reg = 0; reg < 4; ++reg) {
                int rl = wr + ri * 16 + q4 * 4 + reg;
                dotbuf[rl][w & 1] = dotA[ri][reg];
            }
    }
    __syncthreads();

#pragma unroll
    for (int q = 0; q < 4; ++q) {
        int idx = q * 256 + tid;        // 0..1023
        int row = idx >> 4;             // 0..63
        int gc = idx & 15;
        int dwb = (gc * 4) ^ ((row & 12) << 1);
        uint4 vv = *(const uint4*)(So + row * 128 + dwb * 2);
        int grow = r0 + row;
        if (grow < N) *(uint4*)(Hout + (size_t)grow * 128 + gc * 8) = vv;
    }
    if (dodot && tid < 64) {
        int grow = r0 + tid;
        if (grow < N) h1a[grow] = dotbuf[tid][0] + dotbuf[tid][1] + cnextp[0];
    }
}

// ---------------- aggregation: gather in h-space -> g ----------------
__global__ __launch_bounds__(256) void k_agg(
    const unsigned short* __restrict__ xh, const unsigned short* __restrict__ xl,
    const unsigned short* __restrict__ table,
    const float* __restrict__ x1a, const float* __restrict__ xa2a,
    const float* __restrict__ h1a, const int* __restrict__ rp,
    const int* __restrict__ ts,
    unsigned short* __restrict__ g_out, int N) {
    __shared__ uint2 ew[4][64];
    const int wid = threadIdx.x >> 6;
    const int lane = threadIdx.x & 63;
    const int u = blockIdx.x * 4 + wid;
    if (u >= N) return;
    const int l2 = lane << 1;
    float x1u = x1a[u];
    float w2 = expf(lrelu02(x1u + xa2a[u]));
    // self term: full-precision x from hi/lo planes
    unsigned int sh = *(const unsigned int*)(xh + (size_t)u * 128 + l2);
    unsigned int sl = *(const unsigned int*)(xl + (size_t)u * 128 + l2);
    float2 hx = bf2f2(sh), lx = bf2f2(sl);
    float accx = w2 * (hx.x + lx.x), accy = w2 * (hx.y + lx.y);
    float div = w2;
    int p0 = rp[u], p1 = rp[u + 1];
    for (int base = p0; base < p1; base += 64) {
        int e = base + lane;
        uint2 pk = make_uint2(0u, 0u);
        if (e < p1) {
            int tv = ts[e];
            pk.x = (unsigned int)tv;
            pk.y = __float_as_uint(expf(lrelu02(x1u + h1a[tv])));
        }
        ew[wid][lane] = pk;
        int m = p1 - base; if (m > 64) m = 64;
        int m8 = (m + 7) & ~7;
        for (int j = 0; j < m8; j += 8) {
            uint2 q[8];
#pragma unroll
            for (int k = 0; k < 8; ++k) q[k] = ew[wid][j + k];
            unsigned int hv[8];
#pragma unroll
            for (int k = 0; k < 8; ++k)
                hv[k] = *(const unsigned int*)(table + (size_t)q[k].x * 128 + l2);
#pragma unroll
            for (int k = 0; k < 8; ++k) {
                float ww = __uint_as_float(q[k].y);
                float2 f = bf2f2(hv[k]);
                accx = fmaf(ww, f.x, accx);
                accy = fmaf(ww, f.y, accy);
                div += ww;
            }
        }
    }
    float ox = accx / div, oy = accy / div;
    *(unsigned int*)(g_out + (size_t)u * 128 + l2) = f2bf(ox) | (f2bf(oy) << 16);
}

// ---------------- fc2: barrier-free, zero-LDS, 2-term, BM=64 ----------------
__global__ __launch_bounds__(256) void k_fc2(
    const unsigned short* __restrict__ Xhi,
    const unsigned short* __restrict__ Wh, const unsigned short* __restrict__ Wl,
    const float* __restrict__ bias, float* __restrict__ Yf, int N) {
    const int tid = threadIdx.x;
    const int r0 = blockIdx.x * 64;
    const int lane = tid & 63;
    const int w = tid >> 6;
    const int wr = w * 16;
    const int frow = lane & 15;
    const int fk = lane >> 4;
    const int q4 = lane >> 4;

    f32x4 acc[4];
#pragma unroll
    for (int j = 0; j < 4; ++j) acc[j] = (f32x4){0.f, 0.f, 0.f, 0.f};

    const short8 z8 = (short8){0, 0, 0, 0, 0, 0, 0, 0};
#pragma unroll
    for (int kc = 0; kc < 4; ++kc) {
        int row = r0 + wr + frow;
        short8 ah = (row < N) ? *(const short8*)(Xhi + (size_t)row * 128 + kc * 32 + fk * 8) : z8;
#pragma unroll
        for (int ci = 0; ci < 4; ++ci) {
            int col = ci * 16 + frow;
            short8 bh = *(const short8*)(Wh + (size_t)col * 128 + kc * 32 + fk * 8);
            short8 bl = *(const short8*)(Wl + (size_t)col * 128 + kc * 32 + fk * 8);
            acc[ci] = MFMA16(ah, bh, acc[ci], 0, 0, 0);
            acc[ci] = MFMA16(ah, bl, acc[ci], 0, 0, 0);
        }
    }

#pragma unroll
    for (int ci = 0; ci < 4; ++ci) {
        int col = ci * 16 + frow;
        float bcol = bias[col];
#pragma unroll
        for (int reg = 0; reg < 4; ++reg) {
            int grow = r0 + wr + q4 * 4 + reg;
            if (grow < N) Yf[(size_t)grow * 64 + col] = acc[ci][reg] + bcol;
        }
    }
}

// ---------------- launch ----------------
extern "C" void kernel_launch(void* const* d_in, const int* in_sizes, int n_in,
                              void* d_out, int out_size, void* d_ws, size_t ws_size,
                              hipStream_t stream) {
    const float* x_in = (const float*)d_in[0];
    const int*   s    = (const int*)d_in[1];
    const int*   t    = (const int*)d_in[2];
    const float* fc1W = (const float*)d_in[3];
    const float* fc1b = (const float*)d_in[4];
    const float* fcsW = (const float*)d_in[5];
    const float* fcsb = (const float*)d_in[6];
    const float* a1   = (const float*)d_in[7];
    const float* a2   = (const float*)d_in[8];
    const float* fc2W = (const float*)d_in[9];
    const float* fc2b = (const float*)d_in[10];

    const int N = in_sizes[0] / 256;  // 50000
    const int E = in_sizes[1];        // 800000
    const int G = (N + 255) / 256;
    const int NB64 = (N + 63) / 64;   // 782

    char* ws = (char*)d_ws;
    size_t off = 0;
    auto alloc = [&](size_t bytes) -> void* {
        void* p = ws + off;
        off += (bytes + 255) & ~(size_t)255;
        return p;
    };
    unsigned short* xbuf_hi = (unsigned short*)alloc((size_t)N * 128 * 2);
    unsigned short* xbuf_lo = (unsigned short*)alloc((size_t)N * 128 * 2);
    unsigned short* h_hi    = (unsigned short*)alloc((size_t)N * 128 * 2);
    unsigned short* gbuf    = (unsigned short*)alloc((size_t)N * 128 * 2);
    unsigned short* Whi  = (unsigned short*)alloc((size_t)10 * 16384 * 2);
    unsigned short* Wlo  = (unsigned short*)alloc((size_t)10 * 16384 * 2);
    unsigned short* W1hi = (unsigned short*)alloc((size_t)128 * 256 * 2);
    unsigned short* W1lo = (unsigned short*)alloc((size_t)128 * 256 * 2);
    unsigned short* W2hi = (unsigned short*)alloc((size_t)64 * 128 * 2);
    unsigned short* W2lo = (unsigned short*)alloc((size_t)64 * 128 * 2);
    float* Vf   = (float*)alloc((size_t)32 * 128 * 4);
    unsigned short* Vh = (unsigned short*)alloc((size_t)32 * 128 * 2);
    unsigned short* Vl = (unsigned short*)alloc((size_t)32 * 128 * 2);
    float* cvec = (float*)alloc((size_t)32 * 4);
    float* x1a_all  = (float*)alloc((size_t)10 * N * 4);
    float* xa2a_all = (float*)alloc((size_t)10 * N * 4);
    float* h1a  = (float*)alloc((size_t)N * 4);
    int* row_ptr  = (int*)alloc((size_t)(N + 1) * 4);
    int* cnt      = (int*)alloc((size_t)N * 4);
    int* bsums    = (int*)alloc((size_t)1024);
    int* t_sorted = (int*)alloc((size_t)E * 4);

    // CSR build
    hipMemsetAsync(cnt, 0, (size_t)N * 4, stream);
    k_count<<<(E + 255) / 256, 256, 0, stream>>>(s, cnt, E);
    k_scan1<<<G, 256, 0, stream>>>(cnt, bsums, N);
    k_scan2<<<1, 256, 0, stream>>>(bsums, G);
    k_scan3<<<G, 256, 0, stream>>>(cnt, bsums, row_ptr, N);
    hipMemsetAsync(cnt, 0, (size_t)N * 4, stream);
    k_scatter<<<(E + 255) / 256, 256, 0, stream>>>(s, t, row_ptr, cnt, t_sorted, E);

    // W splits + V prep (zero V planes first: rows 10-15/26-31 unused)
    k_wsplit<<<(10 * 16384 + 255) / 256, 256, 0, stream>>>(fcsW, Whi, Wlo, 10 * 16384);
    k_wsplit<<<(128 * 256 + 255) / 256, 256, 0, stream>>>(fc1W, W1hi, W1lo, 128 * 256);
    k_wsplit<<<(64 * 128 + 255) / 256, 256, 0, stream>>>(fc2W, W2hi, W2lo, 64 * 128);
    hipMemsetAsync(Vf, 0, (size_t)32 * 128 * 4, stream);
    hipMemsetAsync(Vh, 0, (size_t)32 * 128 * 2, stream);
    hipMemsetAsync(Vl, 0, (size_t)32 * 128 * 2, stream);
    hipMemsetAsync(cvec, 0, (size_t)32 * 4, stream);
    k_prep<<<10, 256, 0, stream>>>(fcsW, fcsb, a1, a2, Vf, Vh, Vl, cvec);

    // fc1 + relu -> split planes
    k_fc1<<<NB64, 256, 0, stream>>>(x_in, W1hi, W1lo, fc1b, xbuf_hi, xbuf_lo, N);

    // x-side scalars for all hops
    k_xdots<<<NB64, 256, 0, stream>>>(xbuf_hi, xbuf_lo, Vh, Vl, cvec,
                                      x1a_all, xa2a_all, N);

    // hops: k_agg (gather in h-space) -> k_gemm (g -> h_next, fused h1a)
    for (int i = 0; i < 10; ++i) {
        const unsigned short* table = (i == 0) ? xbuf_hi : h_hi;
        const float* h1_i = (i == 0) ? (xa2a_all + 0) : h1a;
        k_agg<<<(N + 3) / 4, 256, 0, stream>>>(xbuf_hi, xbuf_lo, table,
                                               x1a_all + (size_t)i * N,
                                               xa2a_all + (size_t)i * N,
                                               h1_i, row_ptr, t_sorted, gbuf, N);
        const float* vnext = (i < 9) ? (Vf + (size_t)(16 + i + 1) * 128) : nullptr;
        const float* cnextp = cvec + (16 + i + 1);
        k_gemm<<<NB64, 256, 0, stream>>>(gbuf, Whi + (size_t)i * 16384,
                                         Wlo + (size_t)i * 16384,
                                         fcsb + (size_t)i * 128, vnext, cnextp,
                                         h_hi, h1a, N);
    }

    // fc2
    k_fc2<<<NB64, 256, 0, stream>>>(h_hi, W2hi, W2lo, fc2b, (float*)d_out, N);
}

// Round 12
// 789.705 us; speedup vs baseline: 1.4895x; 1.0210x over previous
//
#include <hip/hip_runtime.h>
#include <math.h>

// ---------------------------------------------------------------------------
// GTAN2 R12: fused per-hop kernel k_hop = {gather g (64 rows, into LDS)} ->
// {GEMM g@W^T + elu + next-hop h1 dot}. Removes gbuf round-trip + 10
// launches; needs h/h1a ping-pong (cross-block race otherwise). Self term
// bf16 (xh only). fc1 epilogue staged in LDS -> dense stores (fix 2x write
// amplification). fc2/xdots/prep/CSR unchanged from R11.
// ---------------------------------------------------------------------------

typedef __attribute__((ext_vector_type(8))) short short8;
typedef __attribute__((ext_vector_type(4))) float f32x4;
#define MFMA16 __builtin_amdgcn_mfma_f32_16x16x32_bf16

__device__ __forceinline__ float lrelu02(float v) { return v > 0.f ? v : 0.2f * v; }

__device__ __forceinline__ float2 bf2f2(unsigned int v) {
    return make_float2(__uint_as_float(v << 16), __uint_as_float(v & 0xffff0000u));
}
__device__ __forceinline__ unsigned int f2bf(float f) {  // RNE bf16
    unsigned int u = __float_as_uint(f);
    u += 0x7fffu + ((u >> 16) & 1u);
    return u >> 16;
}
__device__ __forceinline__ float hi_part(float f) {
    return __uint_as_float(__float_as_uint(f) & 0xffff0000u);
}
__device__ __forceinline__ uint4 pack_hi(const float4& a, const float4& b) {
    uint4 r;
    r.x = (__float_as_uint(a.x) >> 16) | (__float_as_uint(a.y) & 0xffff0000u);
    r.y = (__float_as_uint(a.z) >> 16) | (__float_as_uint(a.w) & 0xffff0000u);
    r.z = (__float_as_uint(b.x) >> 16) | (__float_as_uint(b.y) & 0xffff0000u);
    r.w = (__float_as_uint(b.z) >> 16) | (__float_as_uint(b.w) & 0xffff0000u);
    return r;
}
__device__ __forceinline__ uint4 pack_lo(const float4& a, const float4& b) {
    uint4 r;
    r.x = f2bf(a.x - hi_part(a.x)) | (f2bf(a.y - hi_part(a.y)) << 16);
    r.y = f2bf(a.z - hi_part(a.z)) | (f2bf(a.w - hi_part(a.w)) << 16);
    r.z = f2bf(b.x - hi_part(b.x)) | (f2bf(b.y - hi_part(b.y)) << 16);
    r.w = f2bf(b.z - hi_part(b.z)) | (f2bf(b.w - hi_part(b.w)) << 16);
    return r;
}

// ---------------- CSR build ----------------
__global__ __launch_bounds__(256) void k_count(const int* __restrict__ s, int* __restrict__ cnt, int E) {
    int e = blockIdx.x * 256 + threadIdx.x;
    if (e < E) atomicAdd(&cnt[s[e]], 1);
}

__global__ __launch_bounds__(256) void k_scan1(const int* __restrict__ cnt, int* __restrict__ bs, int N) {
    __shared__ int sh[256];
    int idx = blockIdx.x * 256 + threadIdx.x;
    sh[threadIdx.x] = (idx < N) ? cnt[idx] : 0;
    __syncthreads();
#pragma unroll
    for (int off = 128; off; off >>= 1) {
        if (threadIdx.x < off) sh[threadIdx.x] += sh[threadIdx.x + off];
        __syncthreads();
    }
    if (threadIdx.x == 0) bs[blockIdx.x] = sh[0];
}

__global__ __launch_bounds__(256) void k_scan2(int* __restrict__ bs, int G) {
    __shared__ int sh[256];
    int t = threadIdx.x;
    int v = (t < G) ? bs[t] : 0;
    sh[t] = v;
    __syncthreads();
    int val = v;
#pragma unroll
    for (int off = 1; off < 256; off <<= 1) {
        int o = (t >= off) ? sh[t - off] : 0;
        __syncthreads();
        val += o; sh[t] = val;
        __syncthreads();
    }
    if (t < G) bs[t] = val - v;  // exclusive
}

__global__ __launch_bounds__(256) void k_scan3(const int* __restrict__ cnt, const int* __restrict__ bs,
                                               int* __restrict__ rp, int N) {
    __shared__ int sh[256];
    int t = threadIdx.x;
    int idx = blockIdx.x * 256 + t;
    int v = (idx < N) ? cnt[idx] : 0;
    sh[t] = v;
    __syncthreads();
    int val = v;
#pragma unroll
    for (int off = 1; off < 256; off <<= 1) {
        int o = (t >= off) ? sh[t - off] : 0;
        __syncthreads();
        val += o; sh[t] = val;
        __syncthreads();
    }
    if (idx <= N) rp[idx] = val - v + bs[blockIdx.x];
}

__global__ __launch_bounds__(256) void k_scatter(const int* __restrict__ s, const int* __restrict__ t,
                                                 const int* __restrict__ rp, int* __restrict__ cursor,
                                                 int* __restrict__ t_sorted, int E) {
    int e = blockIdx.x * 256 + threadIdx.x;
    if (e < E) {
        int u = s[e];
        int pos = atomicAdd(&cursor[u], 1);
        t_sorted[rp[u] + pos] = t[e];
    }
}

// ---------------- W split ----------------
__global__ __launch_bounds__(256) void k_wsplit(const float* __restrict__ W,
                                                unsigned short* __restrict__ Whi,
                                                unsigned short* __restrict__ Wlo, int total) {
    int i = blockIdx.x * 256 + threadIdx.x;
    if (i < total) {
        float f = W[i];
        unsigned int u = __float_as_uint(f);
        Whi[i] = (unsigned short)(u >> 16);
        Wlo[i] = (unsigned short)f2bf(f - __uint_as_float(u & 0xffff0000u));
    }
}

// ---------------- k_prep: V vectors (W^T a1, W^T a2) + constants ------------
__global__ __launch_bounds__(256) void k_prep(
    const float* __restrict__ fcsW, const float* __restrict__ fcsb,
    const float* __restrict__ a1, const float* __restrict__ a2,
    float* __restrict__ Vf, unsigned short* __restrict__ Vh,
    unsigned short* __restrict__ Vl, float* __restrict__ cvec) {
    int i = blockIdx.x;
    int t = threadIdx.x;
    const float* W = fcsW + (size_t)i * 16384;
    if (t < 128) {
        float s1 = 0.f, s2 = 0.f;
        for (int j = 0; j < 128; ++j) {
            float w = W[j * 128 + t];
            s1 = fmaf(w, a1[i * 128 + j], s1);
            s2 = fmaf(w, a2[i * 128 + j], s2);
        }
        Vf[i * 128 + t] = s1;
        Vf[(16 + i) * 128 + t] = s2;
        Vh[i * 128 + t] = (unsigned short)(__float_as_uint(s1) >> 16);
        Vl[i * 128 + t] = (unsigned short)f2bf(s1 - hi_part(s1));
        Vh[(16 + i) * 128 + t] = (unsigned short)(__float_as_uint(s2) >> 16);
        Vl[(16 + i) * 128 + t] = (unsigned short)f2bf(s2 - hi_part(s2));
    } else if (t == 128) {
        float c1 = 0.f, c2 = 0.f;
        for (int j = 0; j < 128; ++j) {
            c1 = fmaf(fcsb[i * 128 + j], a1[i * 128 + j], c1);
            c2 = fmaf(fcsb[i * 128 + j], a2[i * 128 + j], c2);
        }
        cvec[i] = c1;
        cvec[16 + i] = c2;
    }
}

// ---------------- fc1: 3-term, BM=64, staged dense stores ----------------
__global__ __launch_bounds__(256) void k_fc1(
    const float* __restrict__ Xf,
    const unsigned short* __restrict__ Wh, const unsigned short* __restrict__ Wl,
    const float* __restrict__ bias,
    unsigned short* __restrict__ Yhi, unsigned short* __restrict__ Ylo, int N) {
    __shared__ unsigned short Shi[64 * 128];  // 16 KB
    __shared__ unsigned short Slo[64 * 128];  // 16 KB
    const int tid = threadIdx.x;
    const int r0 = blockIdx.x * 64;
    const int lane = tid & 63;
    const int w = tid >> 6;
    const int wr = (w >> 1) * 32, wc = (w & 1) * 64;
    const int frow = lane & 15;
    const int fk = lane >> 4;
    const int q4 = lane >> 4;

    f32x4 acc[2][4];
#pragma unroll
    for (int i = 0; i < 2; ++i)
#pragma unroll
        for (int j = 0; j < 4; ++j) acc[i][j] = (f32x4){0.f, 0.f, 0.f, 0.f};

    const float4 z4 = make_float4(0.f, 0.f, 0.f, 0.f);
#pragma unroll
    for (int kc = 0; kc < 8; ++kc) {
        short8 ah[2], al[2];
#pragma unroll
        for (int ri = 0; ri < 2; ++ri) {
            int row = r0 + wr + ri * 16 + frow;
            float4 va = z4, vb = z4;
            if (row < N) {
                const float* p = Xf + (size_t)row * 256 + kc * 32 + fk * 8;
                va = *(const float4*)p;
                vb = *(const float4*)(p + 4);
            }
            uint4 h = pack_hi(va, vb);
            uint4 l = pack_lo(va, vb);
            ah[ri] = *(short8*)&h;
            al[ri] = *(short8*)&l;
        }
#pragma unroll
        for (int ci = 0; ci < 4; ++ci) {
            int col = wc + ci * 16 + frow;
            short8 bh = *(const short8*)(Wh + (size_t)col * 256 + kc * 32 + fk * 8);
            short8 bl = *(const short8*)(Wl + (size_t)col * 256 + kc * 32 + fk * 8);
#pragma unroll
            for (int ri = 0; ri < 2; ++ri) {
                acc[ri][ci] = MFMA16(ah[ri], bh, acc[ri][ci], 0, 0, 0);
                acc[ri][ci] = MFMA16(ah[ri], bl, acc[ri][ci], 0, 0, 0);
                acc[ri][ci] = MFMA16(al[ri], bh, acc[ri][ci], 0, 0, 0);
            }
        }
    }

#pragma unroll
    for (int ci = 0; ci < 4; ++ci) {
        int col = wc + ci * 16 + frow;
        float bcol = bias[col];
#pragma unroll
        for (int ri = 0; ri < 2; ++ri) {
            f32x4 v = acc[ri][ci];
#pragma unroll
            for (int reg = 0; reg < 4; ++reg) {
                float val = fmaxf(v[reg] + bcol, 0.f);
                int row = wr + ri * 16 + q4 * 4 + reg;
                int dw = (col >> 1) ^ ((row & 12) << 1);
                Shi[row * 128 + dw * 2 + (col & 1)] = (unsigned short)(__float_as_uint(val) >> 16);
                Slo[row * 128 + dw * 2 + (col & 1)] = (unsigned short)f2bf(val - hi_part(val));
            }
        }
    }
    __syncthreads();
#pragma unroll
    for (int q = 0; q < 4; ++q) {
        int idx = q * 256 + tid;        // 0..1023
        int row = idx >> 4;
        int gc = idx & 15;
        int dwb = (gc * 4) ^ ((row & 12) << 1);
        int grow = r0 + row;
        if (grow < N) {
            *(uint4*)(Yhi + (size_t)grow * 128 + gc * 8) = *(const uint4*)(Shi + row * 128 + dwb * 2);
            *(uint4*)(Ylo + (size_t)grow * 128 + gc * 8) = *(const uint4*)(Slo + row * 128 + dwb * 2);
        }
    }
}

// ---------------- k_xdots: x1a/xa2a for ALL hops in one N x 32 GEMM ---------
__global__ __launch_bounds__(256) void k_xdots(
    const unsigned short* __restrict__ Xhi, const unsigned short* __restrict__ Xlo,
    const unsigned short* __restrict__ Vh, const unsigned short* __restrict__ Vl,
    const float* __restrict__ cvec,
    float* __restrict__ x1a_all, float* __restrict__ xa2a_all, int N) {
    const int tid = threadIdx.x;
    const int r0 = blockIdx.x * 64;
    const int lane = tid & 63;
    const int w = tid >> 6;
    const int wr = w * 16;
    const int frow = lane & 15;
    const int fk = lane >> 4;
    const int q4 = lane >> 4;

    f32x4 acc[2];
    acc[0] = (f32x4){0.f, 0.f, 0.f, 0.f};
    acc[1] = (f32x4){0.f, 0.f, 0.f, 0.f};

    const short8 z8 = (short8){0, 0, 0, 0, 0, 0, 0, 0};
#pragma unroll
    for (int kc = 0; kc < 4; ++kc) {
        int row = r0 + wr + frow;
        bool ok = row < N;
        short8 ah = ok ? *(const short8*)(Xhi + (size_t)row * 128 + kc * 32 + fk * 8) : z8;
        short8 al = ok ? *(const short8*)(Xlo + (size_t)row * 128 + kc * 32 + fk * 8) : z8;
#pragma unroll
        for (int ci = 0; ci < 2; ++ci) {
            int col = ci * 16 + frow;
            short8 bh = *(const short8*)(Vh + (size_t)col * 128 + kc * 32 + fk * 8);
            short8 bl = *(const short8*)(Vl + (size_t)col * 128 + kc * 32 + fk * 8);
            acc[ci] = MFMA16(ah, bh, acc[ci], 0, 0, 0);
            acc[ci] = MFMA16(ah, bl, acc[ci], 0, 0, 0);
            acc[ci] = MFMA16(al, bh, acc[ci], 0, 0, 0);
        }
    }

#pragma unroll
    for (int ci = 0; ci < 2; ++ci) {
        int col = ci * 16 + frow;
        float c = cvec[col];
#pragma unroll
        for (int reg = 0; reg < 4; ++reg) {
            int grow = r0 + wr + q4 * 4 + reg;
            if (grow < N) {
                float val = acc[ci][reg] + c;
                if (col < 10) x1a_all[(size_t)col * N + grow] = val;
                else if (col >= 16 && col < 26) xa2a_all[(size_t)(col - 16) * N + grow] = val;
            }
        }
    }
}

// ---------------- k_hop: fused gather + GEMM + elu + next h1 dot ------------
// Phase 1: each wave gathers g for 16 of the block's 64 rows -> LDS (bf16,
// granule-swizzled). Phase 2: h_next = elu(g @ W^T + b) from LDS A-frags,
// fused next-hop h1 dot. gS reused as C-stage in the epilogue.
__global__ __launch_bounds__(256) void k_hop(
    const unsigned short* __restrict__ table, const unsigned short* __restrict__ xh,
    const float* __restrict__ x1a, const float* __restrict__ xa2a,
    const float* __restrict__ h1in,
    const int* __restrict__ rp, const int* __restrict__ ts,
    const unsigned short* __restrict__ Wh, const unsigned short* __restrict__ Wl,
    const float* __restrict__ bias, const float* __restrict__ vnext,
    const float* __restrict__ cnextp,
    unsigned short* __restrict__ Hout, float* __restrict__ h1out, int N) {
    __shared__ unsigned short gS[64 * 128];  // 16 KB: g tile, then C-stage
    __shared__ uint2 ew[4][64];
    __shared__ float dotbuf[64][2];
    const int tid = threadIdx.x;
    const int wid = tid >> 6;
    const int lane = tid & 63;
    const int r0 = blockIdx.x * 64;

    // ---- phase 1: gather ----
    for (int j = 0; j < 16; ++j) {
        int gr = wid * 16 + j;
        int u = r0 + gr;
        unsigned int packed = 0u;
        if (u < N) {
            float x1u = x1a[u];
            float w2 = expf(lrelu02(x1u + xa2a[u]));
            float2 xr = bf2f2(*(const unsigned int*)(xh + (size_t)u * 128 + lane * 2));
            float accx = w2 * xr.x, accy = w2 * xr.y;
            float div = w2;
            int p0 = rp[u], p1 = rp[u + 1];
            for (int base = p0; base < p1; base += 64) {
                int e = base + lane;
                uint2 pk = make_uint2(0u, 0u);
                if (e < p1) {
                    int tv = ts[e];
                    pk.x = (unsigned int)tv;
                    pk.y = __float_as_uint(expf(lrelu02(x1u + h1in[tv])));
                }
                ew[wid][lane] = pk;
                int m = p1 - base; if (m > 64) m = 64;
                int m8 = (m + 7) & ~7;
                for (int jj = 0; jj < m8; jj += 8) {
                    uint2 q[8];
#pragma unroll
                    for (int k = 0; k < 8; ++k) q[k] = ew[wid][jj + k];
                    unsigned int hv[8];
#pragma unroll
                    for (int k = 0; k < 8; ++k)
                        hv[k] = *(const unsigned int*)(table + (size_t)q[k].x * 128 + lane * 2);
#pragma unroll
                    for (int k = 0; k < 8; ++k) {
                        float ww = __uint_as_float(q[k].y);
                        float2 f = bf2f2(hv[k]);
                        accx = fmaf(ww, f.x, accx);
                        accy = fmaf(ww, f.y, accy);
                        div += ww;
                    }
                }
            }
            float ox = accx / div, oy = accy / div;
            packed = f2bf(ox) | (f2bf(oy) << 16);
        }
        int dw = (((lane >> 2) ^ (gr & 7)) << 2) | (lane & 3);
        *((unsigned int*)gS + gr * 64 + dw) = packed;
    }
    __syncthreads();

    // ---- phase 2: GEMM ----
    const int w = wid;
    const int wr = (w >> 1) * 32, wc = (w & 1) * 64;
    const int frow = lane & 15;
    const int fk = lane >> 4;
    const int q4 = lane >> 4;
    const bool dodot = vnext != nullptr;

    f32x4 acc[2][4];
#pragma unroll
    for (int i = 0; i < 2; ++i)
#pragma unroll
        for (int j = 0; j < 4; ++j) acc[i][j] = (f32x4){0.f, 0.f, 0.f, 0.f};

#pragma unroll
    for (int kc = 0; kc < 4; ++kc) {
        short8 ah[2];
#pragma unroll
        for (int ri = 0; ri < 2; ++ri) {
            int row = wr + ri * 16 + frow;
            int gg = kc * 4 + fk;
            ah[ri] = *(const short8*)(gS + row * 128 + ((gg ^ (row & 7)) * 8));
        }
#pragma unroll
        for (int ci = 0; ci < 4; ++ci) {
            int col = wc + ci * 16 + frow;
            short8 bh = *(const short8*)(Wh + (size_t)col * 128 + kc * 32 + fk * 8);
            short8 bl = *(const short8*)(Wl + (size_t)col * 128 + kc * 32 + fk * 8);
#pragma unroll
            for (int ri = 0; ri < 2; ++ri) {
                acc[ri][ci] = MFMA16(ah[ri], bh, acc[ri][ci], 0, 0, 0);
                acc[ri][ci] = MFMA16(ah[ri], bl, acc[ri][ci], 0, 0, 0);
            }
        }
    }
    __syncthreads();  // all A-frag reads done; gS becomes C-stage

    float dotA[2][4] = {};
#pragma unroll
    for (int ci = 0; ci < 4; ++ci) {
        int col = wc + ci * 16 + frow;
        float bcol = bias[col];
        float vc = dodot ? vnext[col] : 0.f;
#pragma unroll
        for (int ri = 0; ri < 2; ++ri) {
            f32x4 v = acc[ri][ci];
#pragma unroll
            for (int reg = 0; reg < 4; ++reg) {
                float val = v[reg] + bcol;
                val = val > 0.f ? val : expf(val) - 1.f;  // elu
                int row = wr + ri * 16 + q4 * 4 + reg;
                int dw = (col >> 1) ^ ((row & 12) << 1);
                gS[row * 128 + dw * 2 + (col & 1)] = (unsigned short)f2bf(val);
                dotA[ri][reg] = fmaf(val, vc, dotA[ri][reg]);
            }
        }
    }
#pragma unroll
    for (int m = 1; m < 16; m <<= 1)
#pragma unroll
        for (int ri = 0; ri < 2; ++ri)
#pragma unroll
            for (int reg = 0; reg < 4; ++reg)
                dotA[ri][reg] += __shfl_xor(dotA[ri][reg], m, 64);
    if (frow == 0) {
#pragma unroll
        for (int ri = 0; ri < 2; ++ri)
#pragma unroll
            for (int reg = 0; reg < 4; ++reg) {
                int rl = wr + ri * 16 + q4 * 4 + reg;
                dotbuf[rl][w & 1] = dotA[ri][reg];
            }
    }
    __syncthreads();

#pragma unroll
    for (int q = 0; q < 4; ++q) {
        int idx = q * 256 + tid;        // 0..1023
        int row = idx >> 4;
        int gc = idx & 15;
        int dwb = (gc * 4) ^ ((row & 12) << 1);
        uint4 vv = *(const uint4*)(gS + row * 128 + dwb * 2);
        int grow = r0 + row;
        if (grow < N) *(uint4*)(Hout + (size_t)grow * 128 + gc * 8) = vv;
    }
    if (dodot && tid < 64) {
        int grow = r0 + tid;
        if (grow < N) h1out[grow] = dotbuf[tid][0] + dotbuf[tid][1] + cnextp[0];
    }
}

// ---------------- fc2: barrier-free, zero-LDS, 2-term, BM=64 ----------------
__global__ __launch_bounds__(256) void k_fc2(
    const unsigned short* __restrict__ Xhi,
    const unsigned short* __restrict__ Wh, const unsigned short* __restrict__ Wl,
    const float* __restrict__ bias, float* __restrict__ Yf, int N) {
    const int tid = threadIdx.x;
    const int r0 = blockIdx.x * 64;
    const int lane = tid & 63;
    const int w = tid >> 6;
    const int wr = w * 16;
    const int frow = lane & 15;
    const int fk = lane >> 4;
    const int q4 = lane >> 4;

    f32x4 acc[4];
#pragma unroll
    for (int j = 0; j < 4; ++j) acc[j] = (f32x4){0.f, 0.f, 0.f, 0.f};

    const short8 z8 = (short8){0, 0, 0, 0, 0, 0, 0, 0};
#pragma unroll
    for (int kc = 0; kc < 4; ++kc) {
        int row = r0 + wr + frow;
        short8 ah = (row < N) ? *(const short8*)(Xhi + (size_t)row * 128 + kc * 32 + fk * 8) : z8;
#pragma unroll
        for (int ci = 0; ci < 4; ++ci) {
            int col = ci * 16 + frow;
            short8 bh = *(const short8*)(Wh + (size_t)col * 128 + kc * 32 + fk * 8);
            short8 bl = *(const short8*)(Wl + (size_t)col * 128 + kc * 32 + fk * 8);
            acc[ci] = MFMA16(ah, bh, acc[ci], 0, 0, 0);
            acc[ci] = MFMA16(ah, bl, acc[ci], 0, 0, 0);
        }
    }

#pragma unroll
    for (int ci = 0; ci < 4; ++ci) {
        int col = ci * 16 + frow;
        float bcol = bias[col];
#pragma unroll
        for (int reg = 0; reg < 4; ++reg) {
            int grow = r0 + wr + q4 * 4 + reg;
            if (grow < N) Yf[(size_t)grow * 64 + col] = acc[ci][reg] + bcol;
        }
    }
}

// ---------------- launch ----------------
extern "C" void kernel_launch(void* const* d_in, const int* in_sizes, int n_in,
                              void* d_out, int out_size, void* d_ws, size_t ws_size,
                              hipStream_t stream) {
    const float* x_in = (const float*)d_in[0];
    const int*   s    = (const int*)d_in[1];
    const int*   t    = (const int*)d_in[2];
    const float* fc1W = (const float*)d_in[3];
    const float* fc1b = (const float*)d_in[4];
    const float* fcsW = (const float*)d_in[5];
    const float* fcsb = (const float*)d_in[6];
    const float* a1   = (const float*)d_in[7];
    const float* a2   = (const float*)d_in[8];
    const float* fc2W = (const float*)d_in[9];
    const float* fc2b = (const float*)d_in[10];

    const int N = in_sizes[0] / 256;  // 50000
    const int E = in_sizes[1];        // 800000
    const int G = (N + 255) / 256;
    const int NB64 = (N + 63) / 64;   // 782

    char* ws = (char*)d_ws;
    size_t off = 0;
    auto alloc = [&](size_t bytes) -> void* {
        void* p = ws + off;
        off += (bytes + 255) & ~(size_t)255;
        return p;
    };
    unsigned short* xbuf_hi = (unsigned short*)alloc((size_t)N * 128 * 2);
    unsigned short* xbuf_lo = (unsigned short*)alloc((size_t)N * 128 * 2);
    unsigned short* hA      = (unsigned short*)alloc((size_t)N * 128 * 2);
    unsigned short* hB      = (unsigned short*)alloc((size_t)N * 128 * 2);
    unsigned short* Whi  = (unsigned short*)alloc((size_t)10 * 16384 * 2);
    unsigned short* Wlo  = (unsigned short*)alloc((size_t)10 * 16384 * 2);
    unsigned short* W1hi = (unsigned short*)alloc((size_t)128 * 256 * 2);
    unsigned short* W1lo = (unsigned short*)alloc((size_t)128 * 256 * 2);
    unsigned short* W2hi = (unsigned short*)alloc((size_t)64 * 128 * 2);
    unsigned short* W2lo = (unsigned short*)alloc((size_t)64 * 128 * 2);
    float* Vf   = (float*)alloc((size_t)32 * 128 * 4);
    unsigned short* Vh = (unsigned short*)alloc((size_t)32 * 128 * 2);
    unsigned short* Vl = (unsigned short*)alloc((size_t)32 * 128 * 2);
    float* cvec = (float*)alloc((size_t)32 * 4);
    float* x1a_all  = (float*)alloc((size_t)10 * N * 4);
    float* xa2a_all = (float*)alloc((size_t)10 * N * 4);
    float* h1aA = (float*)alloc((size_t)N * 4);
    float* h1aB = (float*)alloc((size_t)N * 4);
    int* row_ptr  = (int*)alloc((size_t)(N + 1) * 4);
    int* cnt      = (int*)alloc((size_t)N * 4);
    int* bsums    = (int*)alloc((size_t)1024);
    int* t_sorted = (int*)alloc((size_t)E * 4);

    // CSR build
    hipMemsetAsync(cnt, 0, (size_t)N * 4, stream);
    k_count<<<(E + 255) / 256, 256, 0, stream>>>(s, cnt, E);
    k_scan1<<<G, 256, 0, stream>>>(cnt, bsums, N);
    k_scan2<<<1, 256, 0, stream>>>(bsums, G);
    k_scan3<<<G, 256, 0, stream>>>(cnt, bsums, row_ptr, N);
    hipMemsetAsync(cnt, 0, (size_t)N * 4, stream);
    k_scatter<<<(E + 255) / 256, 256, 0, stream>>>(s, t, row_ptr, cnt, t_sorted, E);

    // W splits + V prep
    k_wsplit<<<(10 * 16384 + 255) / 256, 256, 0, stream>>>(fcsW, Whi, Wlo, 10 * 16384);
    k_wsplit<<<(128 * 256 + 255) / 256, 256, 0, stream>>>(fc1W, W1hi, W1lo, 128 * 256);
    k_wsplit<<<(64 * 128 + 255) / 256, 256, 0, stream>>>(fc2W, W2hi, W2lo, 64 * 128);
    hipMemsetAsync(Vf, 0, (size_t)32 * 128 * 4, stream);
    hipMemsetAsync(Vh, 0, (size_t)32 * 128 * 2, stream);
    hipMemsetAsync(Vl, 0, (size_t)32 * 128 * 2, stream);
    hipMemsetAsync(cvec, 0, (size_t)32 * 4, stream);
    k_prep<<<10, 256, 0, stream>>>(fcsW, fcsb, a1, a2, Vf, Vh, Vl, cvec);

    // fc1 + relu -> split planes
    k_fc1<<<NB64, 256, 0, stream>>>(x_in, W1hi, W1lo, fc1b, xbuf_hi, xbuf_lo, N);

    // x-side scalars for all hops
    k_xdots<<<NB64, 256, 0, stream>>>(xbuf_hi, xbuf_lo, Vh, Vl, cvec,
                                      x1a_all, xa2a_all, N);

    // hops: fused gather + GEMM, ping-pong h / h1a
    const unsigned short* table = xbuf_hi;
    const float* h1in = xa2a_all;  // hop 0: h1 == xa2 (h == x)
    for (int i = 0; i < 10; ++i) {
        unsigned short* hout = (i & 1) ? hB : hA;
        float* h1out = (i & 1) ? h1aB : h1aA;
        const float* vnext = (i < 9) ? (Vf + (size_t)(16 + i + 1) * 128) : nullptr;
        k_hop<<<NB64, 256, 0, stream>>>(table, xbuf_hi,
                                        x1a_all + (size_t)i * N, xa2a_all + (size_t)i * N,
                                        h1in, row_ptr, t_sorted,
                                        Whi + (size_t)i * 16384, Wlo + (size_t)i * 16384,
                                        fcsb + (size_t)i * 128, vnext, cvec + (16 + i + 1),
                                        hout, h1out, N);
        table = hout;
        h1in = h1out;
    }

    // fc2
    k_fc2<<<NB64, 256, 0, stream>>>(table, W2hi, W2lo, fc2b, (float*)d_out, N);
}